// Round 2
// baseline (1190.811 us; speedup 1.0000x reference)
//
#include <hip/hip_runtime.h>
#include <stdint.h>
#include <math.h>

typedef unsigned short u16;
typedef __attribute__((ext_vector_type(8))) short bf16x8;   // 8 bf16 in 4 VGPRs
typedef __attribute__((ext_vector_type(4))) float f32x4;

__device__ __forceinline__ u16 f2b(float f) {
    unsigned u = __float_as_uint(f);
    u = (u + 0x7FFFu + ((u >> 16) & 1u)) >> 16;   // RNE
    return (u16)u;
}

// async global->LDS, 16B per lane. lds must be wave-uniform base; HW writes base + lane*16.
__device__ __forceinline__ void gload16(const void* g, void* lds) {
    __builtin_amdgcn_global_load_lds(
        (const __attribute__((address_space(1))) unsigned int*)(uintptr_t)g,
        (__attribute__((address_space(3))) unsigned int*)(unsigned int)(uintptr_t)lds,
        16, 0, 0);
}

// ---------------------------------------------------------------------------
// GEMM: C[z] = A[z] (MxK, row-major, bf16) @ B[z]^T (B stored NxK row-major, bf16)
// optional bias[n], scale, residual add (f32, with grouped row remap), C f32 or bf16.
// Tiles 128x128, BK=32, 256 threads (4 waves, each 64x64), m97 structure.
// Out-of-range rows/cols: loads clamped (K never padded -> safe), stores masked.
// ---------------------------------------------------------------------------
#define BM 128
#define BN 128
#define BK 32

__global__ __launch_bounds__(256) void gemm_bt(
    const u16* __restrict__ A, const u16* __restrict__ B,
    const float* __restrict__ bias, const float* __restrict__ resid,
    float* __restrict__ Cf, u16* __restrict__ Cb,
    int M, int N, int K, int lda, int ldb, int ldc,
    int nz2,
    long long sA1, long long sA2, long long sB1, long long sB2,
    long long sC1, long long sC2,
    int z0A, int z0B, int z0C,
    float scale, int rgrp, long long rgA, long long rgoff, int ldr)
{
    __shared__ __align__(16) u16 lA[BM * BK];
    __shared__ __align__(16) u16 lB[BN * BK];

    const int tid = threadIdx.x;
    const int wave = tid >> 6;
    const int lane = tid & 63;

    const int tilesN = (N + BN - 1) / BN;
    const int tm = blockIdx.x / tilesN;
    const int tn = blockIdx.x % tilesN;
    const int row0 = tm * BM;
    const int col0 = tn * BN;

    const int zb = blockIdx.y;
    const int zA = z0A + zb, zB = z0B + zb, zC = z0C + zb;
    const u16* Ab = A + (long long)(zA / nz2) * sA1 + (long long)(zA % nz2) * sA2;
    const u16* Bb = B + (long long)(zB / nz2) * sB1 + (long long)(zB % nz2) * sB2;
    const long long cbase = (long long)(zC / nz2) * sC1 + (long long)(zC % nz2) * sC2;

    // staging: issue i covers flat elems [(i*256+tid)*8, +8); row=f/32, col=f%32
    const int f0 = tid * 8;
    const int f1 = (256 + tid) * 8;
    const int sr0 = f0 >> 5, sc0 = f0 & 31;
    const int sr1 = f1 >> 5, sc1 = f1 & 31;

    u16* lA0 = &lA[(wave * 64) * 8];
    u16* lA1 = &lA[2048 + (wave * 64) * 8];
    u16* lB0 = &lB[(wave * 64) * 8];
    u16* lB1 = &lB[2048 + (wave * 64) * 8];

    int ar0 = row0 + sr0; if (ar0 > M - 1) ar0 = M - 1;
    int ar1 = row0 + sr1; if (ar1 > M - 1) ar1 = M - 1;
    int br0 = col0 + sr0; if (br0 > N - 1) br0 = N - 1;
    int br1 = col0 + sr1; if (br1 > N - 1) br1 = N - 1;

    const u16* pa0 = Ab + (long long)ar0 * lda + sc0;
    const u16* pa1 = Ab + (long long)ar1 * lda + sc1;
    const u16* pb0 = Bb + (long long)br0 * ldb + sc0;
    const u16* pb1 = Bb + (long long)br1 * ldb + sc1;

    const int wr = wave >> 1, wc = wave & 1;
    const int fr = lane & 15;
    const int kk = (lane >> 4) * 8;

    f32x4 acc[4][4];
    #pragma unroll
    for (int m = 0; m < 4; ++m)
        #pragma unroll
        for (int n = 0; n < 4; ++n) {
            f32x4 z = {0.f, 0.f, 0.f, 0.f};
            acc[m][n] = z;
        }

    for (int k0 = 0; k0 < K; k0 += BK) {
        gload16(pa0 + k0, lA0);
        gload16(pa1 + k0, lA1);
        gload16(pb0 + k0, lB0);
        gload16(pb1 + k0, lB1);
        __syncthreads();   // compiler emits vmcnt(0) drain before s_barrier

        bf16x8 af[4], bf[4];
        #pragma unroll
        for (int m = 0; m < 4; ++m)
            af[m] = *(const bf16x8*)&lA[(wr * 64 + m * 16 + fr) * BK + kk];
        #pragma unroll
        for (int n = 0; n < 4; ++n)
            bf[n] = *(const bf16x8*)&lB[(wc * 64 + n * 16 + fr) * BK + kk];
        #pragma unroll
        for (int m = 0; m < 4; ++m)
            #pragma unroll
            for (int n = 0; n < 4; ++n)
                acc[m][n] = __builtin_amdgcn_mfma_f32_16x16x32_bf16(af[m], bf[n], acc[m][n], 0, 0, 0);
        __syncthreads();
    }

    // epilogue: C/D layout col=lane&15, row=(lane>>4)*4+j  [verified m89/m91]
    const int orow = row0 + wr * 64;
    const int ocol = col0 + wc * 64;
    #pragma unroll
    for (int m = 0; m < 4; ++m) {
        const int rb = orow + m * 16 + (lane >> 4) * 4;
        #pragma unroll
        for (int n = 0; n < 4; ++n) {
            const int c = ocol + n * 16 + fr;
            const bool cok = (c < N);
            const float bb = (bias && cok) ? bias[c] : 0.f;
            #pragma unroll
            for (int j = 0; j < 4; ++j) {
                const int r = rb + j;
                if (cok && r < M) {
                    float v = acc[m][n][j] * scale + bb;
                    if (resid) {
                        long long ro = (long long)(r / rgrp) * rgA +
                                       (long long)(r % rgrp) * ldr + rgoff + c;
                        v += resid[ro];
                    }
                    long long co = cbase + (long long)r * ldc + c;
                    if (Cb) Cb[co] = f2b(v);
                    else    Cf[co] = v;
                }
            }
        }
    }
}

// ---------------------------------------------------------------------------
// softmax over rows of length L (wave per row). Optionally writes normalized f32
// (Sout, at global row row+rowOffS) and always bf16 P (local row, leading dim ldp).
// ---------------------------------------------------------------------------
template <int L>
__global__ __launch_bounds__(256) void softmax_k(
    const float* S, float* Sout, u16* P, int ldp, long long rows, long long rowOffS)
{
    constexpr int PER = L / 64;
    const int wave = threadIdx.x >> 6, lane = threadIdx.x & 63;
    const long long row = (long long)blockIdx.x * 4 + wave;
    if (row >= rows) return;
    const float* src = S + (row + rowOffS) * L;
    float v[PER];
    float mx = -1e30f;
    #pragma unroll
    for (int i = 0; i < PER; ++i) { v[i] = src[lane + 64 * i]; mx = fmaxf(mx, v[i]); }
    #pragma unroll
    for (int o = 32; o; o >>= 1) mx = fmaxf(mx, __shfl_xor(mx, o));
    float sum = 0.f;
    #pragma unroll
    for (int i = 0; i < PER; ++i) { v[i] = __expf(v[i] - mx); sum += v[i]; }
    #pragma unroll
    for (int o = 32; o; o >>= 1) sum += __shfl_xor(sum, o);
    const float inv = 1.f / sum;
    float* dst = Sout ? (Sout + (row + rowOffS) * L) : nullptr;
    u16* pd = P + row * (long long)ldp;
    #pragma unroll
    for (int i = 0; i < PER; ++i) {
        const float p = v[i] * inv;
        if (dst) dst[lane + 64 * i] = p;
        pd[lane + 64 * i] = f2b(p);
    }
}

// ---------------------------------------------------------------------------
// V (b,l,h*96+d) bf16 -> Vt (b,h,d,l) bf16.  grid = (L/64, B*8)
// ---------------------------------------------------------------------------
__global__ __launch_bounds__(256) void transpose_v(
    const u16* __restrict__ V, u16* __restrict__ Vt, int L)
{
    __shared__ unsigned int t[64 * 97];
    const int z = blockIdx.y;            // b*8+h
    const int b = z >> 3, h = z & 7;
    const int l0 = blockIdx.x * 64;
    const int tid = threadIdx.x;
    for (int i = 0; i < 24; ++i) {
        const int idx = tid + i * 256;   // < 6144
        const int l = idx / 96, d = idx % 96;
        t[l * 97 + d] = V[((long long)(b * L + l0 + l)) * 768 + h * 96 + d];
    }
    __syncthreads();
    for (int i = 0; i < 24; ++i) {
        const int idx = tid + i * 256;
        const int d = idx / 64, l = idx % 64;
        Vt[((long long)z * 96 + d) * L + l0 + l] = (u16)t[l * 97 + d];
    }
}

// ---------------------------------------------------------------------------
// LayerNorm over 768 cols, wave per row. Output row remap: (r/grp)*gA + (r%grp)*ldo + goff.
// ---------------------------------------------------------------------------
__global__ __launch_bounds__(256) void ln_k(
    const float* __restrict__ X, const float* __restrict__ g, const float* __restrict__ b,
    float* __restrict__ outF, u16* __restrict__ outB,
    int rows, int grp, long long gA, long long goff, int ldo)
{
    const int wave = threadIdx.x >> 6, lane = threadIdx.x & 63;
    const int row = blockIdx.x * 4 + wave;
    if (row >= rows) return;
    const float* x = X + (long long)row * 768;
    float v[12], s = 0.f, sq = 0.f;
    #pragma unroll
    for (int i = 0; i < 12; ++i) { v[i] = x[lane + 64 * i]; s += v[i]; sq += v[i] * v[i]; }
    #pragma unroll
    for (int o = 32; o; o >>= 1) { s += __shfl_xor(s, o); sq += __shfl_xor(sq, o); }
    const float mu = s * (1.f / 768.f);
    const float var = sq * (1.f / 768.f) - mu * mu;
    const float inv = rsqrtf(var + 1e-5f);
    const long long ob = (long long)(row / grp) * gA + (long long)(row % grp) * ldo + goff;
    #pragma unroll
    for (int i = 0; i < 12; ++i) {
        const int c = lane + 64 * i;
        const float y = (v[i] - mu) * inv * g[c] + b[c];
        outF[ob + c] = y;
        if (outB) outB[(long long)row * 768 + c] = f2b(y);
    }
}

__global__ __launch_bounds__(256) void conv_f2b(
    const float4* __restrict__ in, u16* __restrict__ out, long long n4)
{
    long long i = (long long)blockIdx.x * 256 + threadIdx.x;
    const long long stride = (long long)gridDim.x * 256;
    for (; i < n4; i += stride) {
        const float4 f = in[i];
        ushort4 u;
        u.x = f2b(f.x); u.y = f2b(f.y); u.z = f2b(f.z); u.w = f2b(f.w);
        ((ushort4*)out)[i] = u;
    }
}

// patch_tok = image_tokens[:,1:,:] -> contiguous bf16 (18432 x 768)
__global__ __launch_bounds__(256) void conv_patch(
    const float* __restrict__ img, u16* __restrict__ out)
{
    long long i = (long long)blockIdx.x * 256 + threadIdx.x;  // float4 index
    const long long n4 = 18432LL * 192;
    const long long stride = (long long)gridDim.x * 256;
    for (; i < n4; i += stride) {
        const long long r = i / 192; const int c4 = (int)(i % 192);
        const long long sr = (r / 576) * 577 + 1 + (r % 576);
        const float4 f = ((const float4*)img)[sr * 192 + c4];
        ushort4 u;
        u.x = f2b(f.x); u.y = f2b(f.y); u.z = f2b(f.z); u.w = f2b(f.w);
        ((ushort4*)out)[i] = u;
    }
}

__global__ __launch_bounds__(256) void cls_copy(
    const float* __restrict__ img, float* __restrict__ out)
{
    const int i = blockIdx.x * 256 + threadIdx.x;   // 32*768
    if (i < 32 * 768) {
        const int b = i / 768, c = i % 768;
        out[(long long)b * 577 * 768 + c] = img[(long long)b * 577 * 768 + c];
    }
}

// ---------------------------------------------------------------------------
static inline void launch_gemm(hipStream_t s,
    const u16* A, const u16* Bm, const float* bias, const float* resid,
    float* Cf, u16* Cb, int M, int N, int K, int lda, int ldb, int ldc,
    int nz2, long long sA1, long long sA2, long long sB1, long long sB2,
    long long sC1, long long sC2, int z0A, int z0B, int z0C, int nz,
    float scale, int rgrp, long long rgA, long long rgoff, int ldr)
{
    const int tilesM = (M + BM - 1) / BM, tilesN = (N + BN - 1) / BN;
    dim3 grid((unsigned)(tilesM * tilesN), (unsigned)nz);
    gemm_bt<<<grid, dim3(256), 0, s>>>(A, Bm, bias, resid, Cf, Cb,
        M, N, K, lda, ldb, ldc, nz2, sA1, sA2, sB1, sB2, sC1, sC2,
        z0A, z0B, z0C, scale, rgrp, rgA, rgoff, ldr);
}

extern "C" void kernel_launch(void* const* d_in, const int* in_sizes, int n_in,
                              void* d_out, int out_size, void* d_ws, size_t ws_size,
                              hipStream_t stream)
{
    (void)in_sizes; (void)n_in; (void)out_size;
    const float* img   = (const float*)d_in[0];
    const float* tac   = (const float*)d_in[1];
    const float* w1in  = (const float*)d_in[2];
    const float* b1in  = (const float*)d_in[3];
    const float* w1out = (const float*)d_in[4];
    const float* b1out = (const float*)d_in[5];
    const float* w2in  = (const float*)d_in[6];
    const float* b2in  = (const float*)d_in[7];
    const float* w2out = (const float*)d_in[8];
    const float* b2out = (const float*)d_in[9];
    const float* lng1  = (const float*)d_in[10];
    const float* lnb1  = (const float*)d_in[11];
    const float* lng2  = (const float*)d_in[12];
    const float* lnb2  = (const float*)d_in[13];
    float* out = (float*)d_out;

    const long long o_tac  = 32LL * 577 * 768;          // 14,180,352
    const long long o_attn = o_tac + 32LL * 256 * 768;  // 20,471,808

    const float qscale = 1.0f / sqrtf(96.0f);

    // ---- workspace arena ----
    char* ws = (char*)d_ws;
    // persistent
    u16* tact_bf   = (u16*)ws;                         // 8192*768
    u16* patch_bf  = tact_bf + 8192LL * 768;           // 18432*768
    u16* w1in_bf   = patch_bf + 18432LL * 768;         // 2304*768
    u16* w1out_bf  = w1in_bf + 2304LL * 768;           // 768*768
    u16* w2in_bf   = w1out_bf + 768LL * 768;
    u16* w2out_bf  = w2in_bf + 2304LL * 768;
    u16* tactnew_bf = w2out_bf + 768LL * 768;          // 8192*768
    char* sbase    = (char*)(tactnew_bf + 8192LL * 768);
    const long long persist_bytes = (long long)(sbase - ws);   // 62,914,560

    // phase-1 scratch
    u16* Q1  = (u16*)sbase;
    u16* K1  = Q1 + 8192LL * 768;
    u16* V1  = K1 + 18432LL * 768;
    u16* Vt1 = V1 + 18432LL * 768;
    u16* AO1 = Vt1 + 18432LL * 768;
    float* O1s = (float*)(AO1 + 8192LL * 768);
    u16* P1  = (u16*)(O1s + 8192LL * 768);             // chunked: (256/NCH1)*147456 elems
    const long long p1fixed = (long long)((char*)P1 - sbase);          // 135,266,304
    // phase-2 scratch (overlays phase 1)
    u16* Q2  = (u16*)sbase;
    u16* K2  = Q2 + 18432LL * 768;
    u16* V2  = K2 + 8192LL * 768;
    u16* Vt2 = V2 + 8192LL * 768;
    u16* AO2 = Vt2 + 8192LL * 768;
    float* O2s = (float*)(AO2 + 18432LL * 768);
    float* SC2 = O2s + 18432LL * 768;                  // chunked: (256/NCH2)*147456 f32
    const long long p2fixed = (long long)((char*)SC2 - sbase);         // 150,994,944

    const long long P1_bytes  = 256LL * 256 * 576 * 2;   // 75.5 MB
    const long long SC2_bytes = 256LL * 576 * 256 * 4;   // 151.0 MB
    const long long avail = (long long)ws_size - persist_bytes;
    auto pick = [&](long long fixed, long long var) -> int {
        for (int c = 1; c <= 32; c <<= 1)
            if (fixed + var / c <= avail) return c;
        return 32;
    };
    const int NCH1 = pick(p1fixed, P1_bytes);
    const int NCH2 = pick(p2fixed, SC2_bytes);

    // ---- conversions ----
    conv_f2b<<<1024, 256, 0, stream>>>((const float4*)tac, tact_bf, 8192LL * 192);
    conv_patch<<<1024, 256, 0, stream>>>(img, patch_bf);
    conv_f2b<<<512, 256, 0, stream>>>((const float4*)w1in, w1in_bf, 2304LL * 192);
    conv_f2b<<<512, 256, 0, stream>>>((const float4*)w1out, w1out_bf, 768LL * 192);
    conv_f2b<<<512, 256, 0, stream>>>((const float4*)w2in, w2in_bf, 2304LL * 192);
    conv_f2b<<<512, 256, 0, stream>>>((const float4*)w2out, w2out_bf, 768LL * 192);
    cls_copy<<<96, 256, 0, stream>>>(img, out);

    // ================= phase 1: t2i MHA (q=tactile, kv=patch) =================
    // Q1 = (tact @ wq^T + bq) * qscale
    launch_gemm(stream, tact_bf, w1in_bf, b1in, nullptr, nullptr, Q1,
        8192, 768, 768, 768, 768, 768, 1, 0, 0, 0, 0, 0, 0, 0, 0, 0, 1,
        qscale, 1, 0, 0, 768);
    launch_gemm(stream, patch_bf, w1in_bf + 768LL * 768, b1in + 768, nullptr, nullptr, K1,
        18432, 768, 768, 768, 768, 768, 1, 0, 0, 0, 0, 0, 0, 0, 0, 0, 1,
        1.0f, 1, 0, 0, 768);
    launch_gemm(stream, patch_bf, w1in_bf + 2LL * 768 * 768, b1in + 1536, nullptr, nullptr, V1,
        18432, 768, 768, 768, 768, 768, 1, 0, 0, 0, 0, 0, 0, 0, 0, 0, 1,
        1.0f, 1, 0, 0, 768);
    transpose_v<<<dim3(9, 256), 256, 0, stream>>>(V1, Vt1, 576);

    // scores1 -> d_out attn region (raw), batched over z=(b,h)
    launch_gemm(stream, Q1, K1, nullptr, nullptr, out + o_attn, nullptr,
        256, 576, 96, 768, 768, 576,
        8, 256LL * 768, 96, 576LL * 768, 96, 1179648LL, 147456LL,
        0, 0, 0, 256, 1.0f, 1, 0, 0, 768);

    {   // softmax (in-place in d_out) + PV, chunked over z
        const int ZC = 256 / NCH1;
        for (int c = 0; c < NCH1; ++c) {
            const int z0 = c * ZC;
            const long long rows = (long long)ZC * 256;
            softmax_k<576><<<(unsigned)(rows / 4), 256, 0, stream>>>(
                out + o_attn, out + o_attn, P1, 576, rows, (long long)z0 * 256);
            launch_gemm(stream, P1, Vt1, nullptr, nullptr, nullptr, AO1,
                256, 96, 576, 576, 576, 768,
                8, 8LL * 256 * 576, 256LL * 576, 8LL * 96 * 576, 96LL * 576,
                256LL * 768, 96,
                0, z0, z0, ZC, 1.0f, 1, 0, 0, 768);
        }
    }
    // O1 = AO1 @ out_w^T + out_b + tact  (f32)
    launch_gemm(stream, AO1, w1out_bf, b1out, tac, O1s, nullptr,
        8192, 768, 768, 768, 768, 768, 1, 0, 0, 0, 0, 0, 0, 0, 0, 0, 1,
        1.0f, 8192, 0, 0, 768);
    // LN1 -> d_out tactile region (f32) + bf16 for phase 2
    ln_k<<<8192 / 4, 256, 0, stream>>>(O1s, lng1, lnb1, out + o_tac, tactnew_bf,
        8192, 8192, 0, 0, 768);

    // ================= phase 2: i2t MHA (q=patch, kv=tactile_new) =================
    launch_gemm(stream, patch_bf, w2in_bf, b2in, nullptr, nullptr, Q2,
        18432, 768, 768, 768, 768, 768, 1, 0, 0, 0, 0, 0, 0, 0, 0, 0, 1,
        qscale, 1, 0, 0, 768);
    launch_gemm(stream, tactnew_bf, w2in_bf + 768LL * 768, b2in + 768, nullptr, nullptr, K2,
        8192, 768, 768, 768, 768, 768, 1, 0, 0, 0, 0, 0, 0, 0, 0, 0, 1,
        1.0f, 1, 0, 0, 768);
    launch_gemm(stream, tactnew_bf, w2in_bf + 2LL * 768 * 768, b2in + 1536, nullptr, nullptr, V2,
        8192, 768, 768, 768, 768, 768, 1, 0, 0, 0, 0, 0, 0, 0, 0, 0, 1,
        1.0f, 1, 0, 0, 768);
    transpose_v<<<dim3(4, 256), 256, 0, stream>>>(V2, Vt2, 256);

    {   // scores2 (f32, ws chunk) -> softmax->bf16 in place -> PV2, chunked over z
        const int ZC = 256 / NCH2;
        for (int c = 0; c < NCH2; ++c) {
            const int z0 = c * ZC;
            launch_gemm(stream, Q2, K2, nullptr, nullptr, SC2, nullptr,
                576, 256, 96, 768, 768, 256,
                8, 576LL * 768, 96, 256LL * 768, 96, 1179648LL, 147456LL,
                z0, z0, 0, ZC, 1.0f, 1, 0, 0, 768);
            const long long rows = (long long)ZC * 576;
            softmax_k<256><<<(unsigned)((rows + 3) / 4), 256, 0, stream>>>(
                SC2, nullptr, (u16*)SC2, 512, rows, 0);
            launch_gemm(stream, (u16*)SC2, Vt2, nullptr, nullptr, nullptr, AO2,
                576, 96, 256, 512, 256, 768,
                8, 8LL * 576 * 512, 576LL * 512, 8LL * 96 * 256, 96LL * 256,
                576LL * 768, 96,
                0, z0, z0, ZC, 1.0f, 1, 0, 0, 768);
        }
    }
    // O2 = AO2 @ out_w2^T + out_b2 + patch_tok (strided resid from image input)
    launch_gemm(stream, AO2, w2out_bf, b2out, img, O2s, nullptr,
        18432, 768, 768, 768, 768, 768, 1, 0, 0, 0, 0, 0, 0, 0, 0, 0, 1,
        1.0f, 576, 577LL * 768, 768, 768);
    // LN2 -> d_out image region, rows b*577+1+p
    ln_k<<<18432 / 4, 256, 0, stream>>>(O2s, lng2, lnb2, out, nullptr,
        18432, 576, 577LL * 768, 768, 768);
}

// Round 3
// 836.228 us; speedup vs baseline: 1.4240x; 1.4240x over previous
//
#include <hip/hip_runtime.h>
#include <stdint.h>
#include <math.h>

typedef unsigned short u16;
typedef __attribute__((ext_vector_type(8))) short bf16x8;   // 8 bf16 in 4 VGPRs
typedef __attribute__((ext_vector_type(4))) float f32x4;

__device__ __forceinline__ u16 f2b(float f) {
    unsigned u = __float_as_uint(f);
    u = (u + 0x7FFFu + ((u >> 16) & 1u)) >> 16;   // RNE
    return (u16)u;
}

// async global->LDS, 16B per lane. lds dest = wave-uniform base + lane*16.
__device__ __forceinline__ void gload16(const void* g, void* lds) {
    __builtin_amdgcn_global_load_lds(
        (const __attribute__((address_space(1))) unsigned int*)(uintptr_t)g,
        (__attribute__((address_space(3))) unsigned int*)(unsigned int)(uintptr_t)lds,
        16, 0, 0);
}

// ---------------------------------------------------------------------------
// GEMM: C = A (MxK bf16 row-major) @ B^T (B stored NxK bf16 row-major)
// + bias[n], *scale, + resid (f32, grouped row remap), C f32 or bf16.
// 128x128 tile, BK=32, 4 waves. All calls use M,N multiples of 128, K mult 32.
// ---------------------------------------------------------------------------
#define BM 128
#define BN 128
#define BK 32

__global__ __launch_bounds__(256) void gemm_bt(
    const u16* __restrict__ A, const u16* __restrict__ B,
    const float* __restrict__ bias, const float* __restrict__ resid,
    float* __restrict__ Cf, u16* __restrict__ Cb,
    int M, int N, int K, int lda, int ldb, int ldc,
    float scale, int rgrp, long long rgA, long long rgoff, int ldr)
{
    __shared__ __align__(16) u16 lA[BM * BK];
    __shared__ __align__(16) u16 lB[BN * BK];

    const int tid = threadIdx.x;
    const int wave = tid >> 6;
    const int lane = tid & 63;

    const int tilesN = N / BN;
    const int tm = blockIdx.x / tilesN;
    const int tn = blockIdx.x % tilesN;
    const int row0 = tm * BM;
    const int col0 = tn * BN;

    const int f0 = tid * 8;
    const int f1 = (256 + tid) * 8;
    const int sr0 = f0 >> 5, sc0 = f0 & 31;
    const int sr1 = f1 >> 5, sc1 = f1 & 31;

    u16* lA0 = &lA[(wave * 64) * 8];
    u16* lA1 = &lA[2048 + (wave * 64) * 8];
    u16* lB0 = &lB[(wave * 64) * 8];
    u16* lB1 = &lB[2048 + (wave * 64) * 8];

    const u16* pa0 = A + (long long)(row0 + sr0) * lda + sc0;
    const u16* pa1 = A + (long long)(row0 + sr1) * lda + sc1;
    const u16* pb0 = B + (long long)(col0 + sr0) * ldb + sc0;
    const u16* pb1 = B + (long long)(col0 + sr1) * ldb + sc1;

    const int wr = wave >> 1, wc = wave & 1;
    const int fr = lane & 15;
    const int kk = (lane >> 4) * 8;

    f32x4 acc[4][4];
    #pragma unroll
    for (int m = 0; m < 4; ++m)
        #pragma unroll
        for (int n = 0; n < 4; ++n) {
            f32x4 z = {0.f, 0.f, 0.f, 0.f};
            acc[m][n] = z;
        }

    for (int k0 = 0; k0 < K; k0 += BK) {
        gload16(pa0 + k0, lA0);
        gload16(pa1 + k0, lA1);
        gload16(pb0 + k0, lB0);
        gload16(pb1 + k0, lB1);
        __syncthreads();

        bf16x8 af[4], bfv[4];
        #pragma unroll
        for (int m = 0; m < 4; ++m)
            af[m] = *(const bf16x8*)&lA[(wr * 64 + m * 16 + fr) * BK + kk];
        #pragma unroll
        for (int n = 0; n < 4; ++n)
            bfv[n] = *(const bf16x8*)&lB[(wc * 64 + n * 16 + fr) * BK + kk];
        #pragma unroll
        for (int m = 0; m < 4; ++m)
            #pragma unroll
            for (int n = 0; n < 4; ++n)
                acc[m][n] = __builtin_amdgcn_mfma_f32_16x16x32_bf16(af[m], bfv[n], acc[m][n], 0, 0, 0);
        __syncthreads();
    }

    // epilogue. C/D layout: col=lane&15, row=(lane>>4)*4+j
    const int orow = row0 + wr * 64;
    const int ocol = col0 + wc * 64;
    const int g4 = (lane >> 4) * 4;
    float bcol[4];
    #pragma unroll
    for (int n = 0; n < 4; ++n)
        bcol[n] = bias ? bias[ocol + n * 16 + fr] : 0.f;

    #pragma unroll
    for (int m = 0; m < 4; ++m) {
        #pragma unroll
        for (int j = 0; j < 4; ++j) {
            const int r = orow + m * 16 + g4 + j;
            long long ro = 0;
            if (resid) {
                unsigned q = (unsigned)r / (unsigned)rgrp;     // 16 divs/thread total
                unsigned rem = (unsigned)r - q * (unsigned)rgrp;
                ro = (long long)q * rgA + (long long)rem * ldr + rgoff;
            }
            const long long crow = (long long)r * ldc;
            #pragma unroll
            for (int n = 0; n < 4; ++n) {
                const int c = ocol + n * 16 + fr;
                float v = acc[m][n][j] * scale + bcol[n];
                if (resid) v += resid[ro + c];
                if (Cb) Cb[crow + c] = f2b(v);
                else    Cf[crow + c] = v;
            }
        }
    }
}

// ---------------------------------------------------------------------------
// Fused attention core: per block = one z=(b,h), one 128-row q-tile.
// Pass A: S^T = K@Q^T tiles -> online row max/sum. Pass B: recompute S = Q@K^T,
// p = exp(s-m)/l, write attn f32 (phase1), P->LDS (overlay Q), PV MFMA.
// kt=64. D=96 fixed. 4 waves: (wr = q-half, wc = k-half / d-half).
// ---------------------------------------------------------------------------
template <bool WATTN>
__global__ __launch_bounds__(256, 2) void fused_attn(
    const u16* __restrict__ Q, const u16* __restrict__ K, const u16* __restrict__ Vt,
    float* __restrict__ attn, u16* __restrict__ O,
    int Lq, int Lk, int ldq, int ldk, int ldo)
{
    __shared__ __align__(16) u16 lQP[128 * 96];   // Q[128][96] then P[128][72] (overlay)
    __shared__ __align__(16) u16 lKt[64 * 96];    // K-tile [64 k][96 d]
    __shared__ __align__(16) u16 lVt[96 * 64];    // V-tile [96 d][64 k], XOR-swizzled
    __shared__ float lM2[2][128], lL2[2][128];

    const int tid = threadIdx.x, wave = tid >> 6, lane = tid & 63;
    const int fr = lane & 15, g = lane >> 4;
    const int wr = wave >> 1, wc = wave & 1;
    const int z = blockIdx.y, b = z >> 3, h = z & 7;
    const int q0 = blockIdx.x * 128;
    const int nt = Lk >> 6;

    const u16* Qz = Q + (long long)b * Lq * ldq + h * 96;
    const u16* Kz = K + (long long)b * Lk * ldk + h * 96;
    const u16* Vz = Vt + (long long)z * 96 * Lk;
    u16* Oz = O + (long long)b * Lq * ldo + h * 96;
    float* Az = attn + (long long)z * Lq * Lk;

    // staging source pointers (per-lane); dest = uniform base + lane*16
    const u16* qsrc[6];
    #pragma unroll
    for (int t = 0; t < 6; ++t) {
        int u = t * 256 + tid;
        int r = u / 12, cu = u % 12;
        int qr = q0 + r; if (qr > Lq - 1) qr = Lq - 1;
        qsrc[t] = Qz + (long long)qr * ldq + cu * 8;
    }
    const u16* ksrc[3];
    #pragma unroll
    for (int t = 0; t < 3; ++t) {
        int u = t * 256 + tid;
        int r = u / 12, cu = u % 12;
        ksrc[t] = Kz + (long long)r * ldk + cu * 8;
    }
    const u16* vsrc[3];
    #pragma unroll
    for (int t = 0; t < 3; ++t) {
        int u = t * 256 + tid;
        int d = u >> 3, uu = u & 7;
        vsrc[t] = Vz + (long long)d * Lk + ((uu ^ (d & 7)) * 8);  // pre-swizzled source
    }
    const long long kstep = 64LL * ldk;

    #define DQ(t) ((char*)lQP + ((t) * 256 + wave * 64) * 16)
    #define DK(t) ((char*)lKt + ((t) * 256 + wave * 64) * 16)
    #define DV(t) ((char*)lVt + ((t) * 256 + wave * 64) * 16)

    // prologue: stage Q (once) and K[0]
    #pragma unroll
    for (int t = 0; t < 6; ++t) gload16(qsrc[t], DQ(t));
    #pragma unroll
    for (int t = 0; t < 3; ++t) gload16(ksrc[t], DK(t));
    __syncthreads();

    // Q fragments -> regs (kept for both passes); frees lQP for P
    bf16x8 qf[4][3];
    #pragma unroll
    for (int m = 0; m < 4; ++m)
        #pragma unroll
        for (int ks = 0; ks < 3; ++ks)
            qf[m][ks] = *(const bf16x8*)((const char*)lQP + (wr * 64 + m * 16 + fr) * 192 + ks * 64 + g * 16);

    // ---------------- pass A: online m,l over k (wave covers its wc k-half) ----
    float m_run[4], l_run[4];
    #pragma unroll
    for (int i = 0; i < 4; ++i) { m_run[i] = -1e30f; l_run[i] = 0.f; }

    for (int i = 0; i < nt; ++i) {
        bf16x8 kf[2][3];
        #pragma unroll
        for (int mk = 0; mk < 2; ++mk)
            #pragma unroll
            for (int ks = 0; ks < 3; ++ks)
                kf[mk][ks] = *(const bf16x8*)((const char*)lKt + (wc * 32 + mk * 16 + fr) * 192 + ks * 64 + g * 16);
        f32x4 sa[2][4];
        #pragma unroll
        for (int mk = 0; mk < 2; ++mk)
            #pragma unroll
            for (int nq = 0; nq < 4; ++nq) {
                f32x4 zz = {0.f, 0.f, 0.f, 0.f};
                sa[mk][nq] = zz;
            }
        #pragma unroll
        for (int ks = 0; ks < 3; ++ks)
            #pragma unroll
            for (int mk = 0; mk < 2; ++mk)
                #pragma unroll
                for (int nq = 0; nq < 4; ++nq)
                    sa[mk][nq] = __builtin_amdgcn_mfma_f32_16x16x32_bf16(kf[mk][ks], qf[nq][ks], sa[mk][nq], 0, 0, 0);
        // S^T: rows k (lane g*4+j per mk-frag), cols q = wr*64+nq*16+fr
        #pragma unroll
        for (int nq = 0; nq < 4; ++nq) {
            float tmx = -1e30f;
            #pragma unroll
            for (int mk = 0; mk < 2; ++mk)
                #pragma unroll
                for (int j = 0; j < 4; ++j)
                    tmx = fmaxf(tmx, sa[mk][nq][j]);
            tmx = fmaxf(tmx, __shfl_xor(tmx, 16));
            tmx = fmaxf(tmx, __shfl_xor(tmx, 32));
            const float mnew = fmaxf(m_run[nq], tmx);
            float ts = 0.f;
            #pragma unroll
            for (int mk = 0; mk < 2; ++mk)
                #pragma unroll
                for (int j = 0; j < 4; ++j)
                    ts += __expf(sa[mk][nq][j] - mnew);
            ts += __shfl_xor(ts, 16);
            ts += __shfl_xor(ts, 32);
            l_run[nq] = l_run[nq] * __expf(m_run[nq] - mnew) + ts;
            m_run[nq] = mnew;
        }
        __syncthreads();                          // all waves done reading lKt[i]
        if (i + 1 < nt) {
            #pragma unroll
            for (int t = 0; t < 3; ++t) { ksrc[t] += kstep; gload16(ksrc[t], DK(t)); }
        }
        __syncthreads();                          // drain -> lKt[i+1] ready
    }

    // publish per-half m,l
    if (g == 0) {
        #pragma unroll
        for (int nq = 0; nq < 4; ++nq) {
            lM2[wc][wr * 64 + nq * 16 + fr] = m_run[nq];
            lL2[wc][wr * 64 + nq * 16 + fr] = l_run[nq];
        }
    }
    // pass-B prologue: rewind K, stage K[0] + V[0]
    #pragma unroll
    for (int t = 0; t < 3; ++t) ksrc[t] -= (long long)(nt - 1) * kstep;
    #pragma unroll
    for (int t = 0; t < 3; ++t) gload16(ksrc[t], DK(t));
    #pragma unroll
    for (int t = 0; t < 3; ++t) gload16(vsrc[t], DV(t));
    __syncthreads();                              // lM2/lL2 visible; K[0],V[0] ready

    // merged m, 1/l for this lane's 16 q-rows
    float mrow[16], linv[16];
    #pragma unroll
    for (int m = 0; m < 4; ++m)
        #pragma unroll
        for (int j = 0; j < 4; ++j) {
            const int q = wr * 64 + m * 16 + g * 4 + j;
            const float ma = lM2[0][q], mb = lM2[1][q];
            const float mm = fmaxf(ma, mb);
            const float ll = lL2[0][q] * __expf(ma - mm) + lL2[1][q] * __expf(mb - mm);
            mrow[m * 4 + j] = mm;
            linv[m * 4 + j] = 1.f / ll;
        }

    // ---------------- pass B: S, normalized p -> attn + LDS, PV ---------------
    f32x4 oacc[4][3];
    #pragma unroll
    for (int m = 0; m < 4; ++m)
        #pragma unroll
        for (int nd = 0; nd < 3; ++nd) {
            f32x4 zz = {0.f, 0.f, 0.f, 0.f};
            oacc[m][nd] = zz;
        }

    for (int i = 0; i < nt; ++i) {
        const int k0 = i * 64;
        bf16x8 kf[2][3];
        #pragma unroll
        for (int n = 0; n < 2; ++n)
            #pragma unroll
            for (int ks = 0; ks < 3; ++ks)
                kf[n][ks] = *(const bf16x8*)((const char*)lKt + (wc * 32 + n * 16 + fr) * 192 + ks * 64 + g * 16);
        f32x4 ss[4][2];
        #pragma unroll
        for (int m = 0; m < 4; ++m)
            #pragma unroll
            for (int n = 0; n < 2; ++n) {
                f32x4 zz = {0.f, 0.f, 0.f, 0.f};
                ss[m][n] = zz;
            }
        #pragma unroll
        for (int ks = 0; ks < 3; ++ks)
            #pragma unroll
            for (int m = 0; m < 4; ++m)
                #pragma unroll
                for (int n = 0; n < 2; ++n)
                    ss[m][n] = __builtin_amdgcn_mfma_f32_16x16x32_bf16(qf[m][ks], kf[n][ks], ss[m][n], 0, 0, 0);
        __syncthreads();                          // done reading lKt[i]
        if (i + 1 < nt) {
            #pragma unroll
            for (int t = 0; t < 3; ++t) { ksrc[t] += kstep; gload16(ksrc[t], DK(t)); }
        }
        // normalized p: write attn (f32) and P (bf16, LDS rows padded to 72)
        #pragma unroll
        for (int m = 0; m < 4; ++m)
            #pragma unroll
            for (int n = 0; n < 2; ++n)
                #pragma unroll
                for (int j = 0; j < 4; ++j) {
                    const float p = __expf(ss[m][n][j] - mrow[m * 4 + j]) * linv[m * 4 + j];
                    const int q = wr * 64 + m * 16 + g * 4 + j;
                    const int k = wc * 32 + n * 16 + fr;
                    if (WATTN) Az[(long long)(q0 + q) * Lk + k0 + k] = p;
                    *(u16*)((char*)lQP + q * 144 + k * 2) = f2b(p);
                }
        __syncthreads();                          // lP visible; K[i+1], V[i] drained
        #pragma unroll
        for (int ks = 0; ks < 2; ++ks) {
            bf16x8 vf[3], pf[4];
            #pragma unroll
            for (int nd = 0; nd < 3; ++nd) {
                const int row = wc * 48 + nd * 16 + fr;
                vf[nd] = *(const bf16x8*)((const char*)lVt + row * 128 + (((ks * 4 + g) ^ (row & 7)) * 16));
            }
            #pragma unroll
            for (int m = 0; m < 4; ++m)
                pf[m] = *(const bf16x8*)((const char*)lQP + (wr * 64 + m * 16 + fr) * 144 + ks * 64 + g * 16);
            #pragma unroll
            for (int m = 0; m < 4; ++m)
                #pragma unroll
                for (int nd = 0; nd < 3; ++nd)
                    oacc[m][nd] = __builtin_amdgcn_mfma_f32_16x16x32_bf16(pf[m], vf[nd], oacc[m][nd], 0, 0, 0);
        }
        __syncthreads();                          // done reading lP, lVt[i]
        if (i + 1 < nt) {
            #pragma unroll
            for (int t = 0; t < 3; ++t) { vsrc[t] += 64; gload16(vsrc[t], DV(t)); }
        }
    }

    // epilogue: O (already normalized since P was)
    #pragma unroll
    for (int m = 0; m < 4; ++m)
        #pragma unroll
        for (int j = 0; j < 4; ++j) {
            const int q = q0 + wr * 64 + m * 16 + g * 4 + j;
            if (q < Lq) {
                #pragma unroll
                for (int nd = 0; nd < 3; ++nd) {
                    const int c = wc * 48 + nd * 16 + fr;
                    Oz[(long long)q * ldo + c] = f2b(oacc[m][nd][j]);
                }
            }
        }
    #undef DQ
    #undef DK
    #undef DV
}

// ---------------------------------------------------------------------------
// V (b,l,vcol+h*96+d in ldv-stride rows) bf16 -> Vt (z=b*8+h, d, l) bf16.
// ---------------------------------------------------------------------------
__global__ __launch_bounds__(256) void transpose_v(
    const u16* __restrict__ V, u16* __restrict__ Vt, int L, int ldv)
{
    __shared__ unsigned int t[64 * 97];
    const int z = blockIdx.y;
    const int b = z >> 3, h = z & 7;
    const int l0 = blockIdx.x * 64;
    const int tid = threadIdx.x;
    for (int i = 0; i < 24; ++i) {
        const int idx = tid + i * 256;
        const int l = idx / 96, d = idx % 96;
        t[l * 97 + d] = V[((long long)(b * L + l0 + l)) * ldv + h * 96 + d];
    }
    __syncthreads();
    for (int i = 0; i < 24; ++i) {
        const int idx = tid + i * 256;
        const int d = idx / 64, l = idx % 64;
        Vt[((long long)z * 96 + d) * L + l0 + l] = (u16)t[l * 97 + d];
    }
}

// ---------------------------------------------------------------------------
__global__ __launch_bounds__(256) void ln_k(
    const float* __restrict__ X, const float* __restrict__ g, const float* __restrict__ b,
    float* __restrict__ outF, u16* __restrict__ outB,
    int rows, int grp, long long gA, long long goff, int ldo)
{
    const int wave = threadIdx.x >> 6, lane = threadIdx.x & 63;
    const int row = blockIdx.x * 4 + wave;
    if (row >= rows) return;
    const float* x = X + (long long)row * 768;
    float v[12], s = 0.f, sq = 0.f;
    #pragma unroll
    for (int i = 0; i < 12; ++i) { v[i] = x[lane + 64 * i]; s += v[i]; sq += v[i] * v[i]; }
    #pragma unroll
    for (int o = 32; o; o >>= 1) { s += __shfl_xor(s, o); sq += __shfl_xor(sq, o); }
    const float mu = s * (1.f / 768.f);
    const float var = sq * (1.f / 768.f) - mu * mu;
    const float inv = rsqrtf(var + 1e-5f);
    const long long ob = (long long)(row / grp) * gA + (long long)(row % grp) * ldo + goff;
    #pragma unroll
    for (int i = 0; i < 12; ++i) {
        const int c = lane + 64 * i;
        const float y = (v[i] - mu) * inv * g[c] + b[c];
        outF[ob + c] = y;
        if (outB) outB[(long long)row * 768 + c] = f2b(y);
    }
}

__global__ __launch_bounds__(256) void conv_f2b(
    const float4* __restrict__ in, u16* __restrict__ out, long long n4)
{
    long long i = (long long)blockIdx.x * 256 + threadIdx.x;
    const long long stride = (long long)gridDim.x * 256;
    for (; i < n4; i += stride) {
        const float4 f = in[i];
        ushort4 u;
        u.x = f2b(f.x); u.y = f2b(f.y); u.z = f2b(f.z); u.w = f2b(f.w);
        ((ushort4*)out)[i] = u;
    }
}

__global__ __launch_bounds__(256) void conv_patch(
    const float* __restrict__ img, u16* __restrict__ out)
{
    long long i = (long long)blockIdx.x * 256 + threadIdx.x;
    const long long n4 = 18432LL * 192;
    const long long stride = (long long)gridDim.x * 256;
    for (; i < n4; i += stride) {
        const long long r = i / 192; const int c4 = (int)(i % 192);
        const long long sr = (r / 576) * 577 + 1 + (r % 576);
        const float4 f = ((const float4*)img)[sr * 192 + c4];
        ushort4 u;
        u.x = f2b(f.x); u.y = f2b(f.y); u.z = f2b(f.z); u.w = f2b(f.w);
        ((ushort4*)out)[i] = u;
    }
}

__global__ __launch_bounds__(256) void cls_copy(
    const float* __restrict__ img, float* __restrict__ out)
{
    const int i = blockIdx.x * 256 + threadIdx.x;
    if (i < 32 * 768) {
        const int b = i / 768, c = i % 768;
        out[(long long)b * 577 * 768 + c] = img[(long long)b * 577 * 768 + c];
    }
}

// ---------------------------------------------------------------------------
static inline void launch_gemm(hipStream_t s,
    const u16* A, const u16* Bm, const float* bias, const float* resid,
    float* Cf, u16* Cb, int M, int N, int K, int lda, int ldb, int ldc,
    float scale, int rgrp, long long rgA, long long rgoff, int ldr)
{
    dim3 grid((unsigned)((M / BM) * (N / BN)));
    gemm_bt<<<grid, dim3(256), 0, s>>>(A, Bm, bias, resid, Cf, Cb,
        M, N, K, lda, ldb, ldc, scale, rgrp, rgA, rgoff, ldr);
}

extern "C" void kernel_launch(void* const* d_in, const int* in_sizes, int n_in,
                              void* d_out, int out_size, void* d_ws, size_t ws_size,
                              hipStream_t stream)
{
    (void)in_sizes; (void)n_in; (void)out_size; (void)ws_size;
    const float* img   = (const float*)d_in[0];
    const float* tac   = (const float*)d_in[1];
    const float* w1in  = (const float*)d_in[2];
    const float* b1in  = (const float*)d_in[3];
    const float* w1out = (const float*)d_in[4];
    const float* b1out = (const float*)d_in[5];
    const float* w2in  = (const float*)d_in[6];
    const float* b2in  = (const float*)d_in[7];
    const float* w2out = (const float*)d_in[8];
    const float* b2out = (const float*)d_in[9];
    const float* lng1  = (const float*)d_in[10];
    const float* lnb1  = (const float*)d_in[11];
    const float* lng2  = (const float*)d_in[12];
    const float* lnb2  = (const float*)d_in[13];
    float* out = (float*)d_out;

    const long long o_tac  = 32LL * 577 * 768;
    const long long o_attn = o_tac + 32LL * 256 * 768;
    const float qscale = 1.0f / sqrtf(96.0f);

    // ---- workspace arena ----
    char* ws = (char*)d_ws;
    u16* tact_bf    = (u16*)ws;                         // 8192*768
    u16* patch_bf   = tact_bf + 8192LL * 768;           // 18432*768
    u16* w1in_bf    = patch_bf + 18432LL * 768;         // 2304*768
    u16* w1out_bf   = w1in_bf + 2304LL * 768;           // 768*768
    u16* w2in_bf    = w1out_bf + 768LL * 768;
    u16* w2out_bf   = w2in_bf + 2304LL * 768;
    u16* tactnew_bf = w2out_bf + 768LL * 768;           // 8192*768
    char* sbase     = (char*)(tactnew_bf + 8192LL * 768);   // persist = 63 MB

    // phase-1 scratch
    u16* Q1  = (u16*)sbase;                 // 8192*768        (12.6 MB)
    u16* KV1 = Q1 + 8192LL * 768;           // 18432*1536      (56.6 MB)
    u16* Vt1 = KV1 + 18432LL * 1536;        // 256*96*576      (28.3 MB)
    u16* AO1 = Vt1 + 256LL * 96 * 576;      // 8192*768        (12.6 MB)
    float* O1s = (float*)Vt1;               // overlay Vt1 (25.2 <= 28.3 MB; Vt1 dead post-attn)
    // phase-2 scratch (overlays phase 1)
    u16* Q2  = (u16*)sbase;                 // 18432*768       (28.3 MB)
    u16* KV2 = Q2 + 18432LL * 768;          // 8192*1536       (25.2 MB)
    u16* Vt2 = KV2 + 8192LL * 1536;         // 256*96*256      (12.6 MB)
    u16* AO2 = Vt2 + 256LL * 96 * 256;      // 18432*768       (28.3 MB)
    float* O2s = (float*)sbase;             // overlay Q2+KV2+part Vt2 (all dead post-attn2)

    // ---- f32 -> bf16 conversions ----
    conv_f2b<<<1024, 256, 0, stream>>>((const float4*)tac, tact_bf, 8192LL * 192);
    conv_patch<<<1024, 256, 0, stream>>>(img, patch_bf);
    conv_f2b<<<512, 256, 0, stream>>>((const float4*)w1in, w1in_bf, 2304LL * 192);
    conv_f2b<<<512, 256, 0, stream>>>((const float4*)w1out, w1out_bf, 768LL * 192);
    conv_f2b<<<512, 256, 0, stream>>>((const float4*)w2in, w2in_bf, 2304LL * 192);
    conv_f2b<<<512, 256, 0, stream>>>((const float4*)w2out, w2out_bf, 768LL * 192);
    cls_copy<<<96, 256, 0, stream>>>(img, out);

    // ================= phase 1: t2i MHA (q=tactile, kv=patch) =================
    launch_gemm(stream, tact_bf, w1in_bf, b1in, nullptr, nullptr, Q1,
        8192, 768, 768, 768, 768, 768, qscale, 1, 0, 0, 0);
    launch_gemm(stream, patch_bf, w1in_bf + 768LL * 768, b1in + 768, nullptr, nullptr, KV1,
        18432, 1536, 768, 768, 768, 1536, 1.0f, 1, 0, 0, 0);
    transpose_v<<<dim3(9, 256), 256, 0, stream>>>(KV1 + 768, Vt1, 576, 1536);
    fused_attn<true><<<dim3(2, 256), 256, 0, stream>>>(
        Q1, KV1, Vt1, out + o_attn, AO1, 256, 576, 768, 1536, 768);
    launch_gemm(stream, AO1, w1out_bf, b1out, tac, O1s, nullptr,
        8192, 768, 768, 768, 768, 768, 1.0f, 1, 768, 0, 0);
    ln_k<<<8192 / 4, 256, 0, stream>>>(O1s, lng1, lnb1, out + o_tac, tactnew_bf,
        8192, 8192, 0, 0, 768);

    // ================= phase 2: i2t MHA (q=patch, kv=tactile_new) =============
    launch_gemm(stream, patch_bf, w2in_bf, b2in, nullptr, nullptr, Q2,
        18432, 768, 768, 768, 768, 768, qscale, 1, 0, 0, 0);
    launch_gemm(stream, tactnew_bf, w2in_bf + 768LL * 768, b2in + 768, nullptr, nullptr, KV2,
        8192, 1536, 768, 768, 768, 1536, 1.0f, 1, 0, 0, 0);
    transpose_v<<<dim3(4, 256), 256, 0, stream>>>(KV2 + 768, Vt2, 256, 1536);
    fused_attn<false><<<dim3(5, 256), 256, 0, stream>>>(
        Q2, KV2, Vt2, nullptr, AO2, 576, 256, 768, 1536, 768);
    launch_gemm(stream, AO2, w2out_bf, b2out, img, O2s, nullptr,
        18432, 768, 768, 768, 768, 768, 1.0f, 576, 577LL * 768, 768, 768);
    ln_k<<<18432 / 4, 256, 0, stream>>>(O2s, lng2, lnb2, out, nullptr,
        18432, 576, 577LL * 768, 768, 768);
}

// Round 6
// 764.821 us; speedup vs baseline: 1.5570x; 1.0934x over previous
//
#include <hip/hip_runtime.h>
#include <stdint.h>
#include <math.h>

typedef unsigned short u16;
typedef __attribute__((ext_vector_type(8))) short bf16x8;   // 8 bf16 in 4 VGPRs
typedef __attribute__((ext_vector_type(4))) float f32x4;

__device__ __forceinline__ u16 f2b(float f) {
    unsigned u = __float_as_uint(f);
    u = (u + 0x7FFFu + ((u >> 16) & 1u)) >> 16;   // RNE
    return (u16)u;
}

// async global->LDS, 16B per lane. lds dest = wave-uniform base + lane*16.
__device__ __forceinline__ void gload16(const void* g, void* lds) {
    __builtin_amdgcn_global_load_lds(
        (const __attribute__((address_space(1))) unsigned int*)(uintptr_t)g,
        (__attribute__((address_space(3))) unsigned int*)(unsigned int)(uintptr_t)lds,
        16, 0, 0);
}

// ---------------------------------------------------------------------------
// Grouped GEMM: up to 3 independent C = A @ B^T (+bias, *scale, +resid) in one
// launch. 128x128 tile, BK=32, double-buffered LDS (stage next before compute),
// XCD-aware bijective block swizzle. All M,N multiples of 128, K mult of 32.
// ---------------------------------------------------------------------------
#define BM 128
#define BN 128
#define BK 32

struct GemmGrp {
    const u16* A; const u16* B; const float* bias; const float* resid;
    float* Cf; u16* Cb;
    int M, N, lda, ldb, ldc;
    float scale;
    int rgrp; long long rgA, rgoff; int ldr;
};
struct G3 { GemmGrp g[3]; int start[4]; int K; };

__global__ __launch_bounds__(256) void gemm_grp(G3 P)
{
    __shared__ __align__(16) u16 lA[2][BM * BK];
    __shared__ __align__(16) u16 lB[2][BN * BK];

    const int tid = threadIdx.x;
    const int wave = tid >> 6;
    const int lane = tid & 63;

    // XCD-aware swizzle (bijective when ntot % 8 == 0: all our grids are)
    const int ntot = P.start[3];
    int L = blockIdx.x;
    if ((ntot & 7) == 0) L = (L & 7) * (ntot >> 3) + (L >> 3);

    const int gi = (L >= P.start[1]) + (L >= P.start[2]);
    GemmGrp g;
    if (gi == 0) g = P.g[0]; else if (gi == 1) g = P.g[1]; else g = P.g[2];
    const int t = L - P.start[gi];

    const int tilesN = g.N / BN;
    const int tm = t / tilesN;
    const int tn = t % tilesN;
    const int row0 = tm * BM;
    const int col0 = tn * BN;

    const int f0 = tid * 8;
    const int f1 = (256 + tid) * 8;
    const int sr0 = f0 >> 5, sc0 = f0 & 31;
    const int sr1 = f1 >> 5, sc1 = f1 & 31;

    const u16* pa0 = g.A + (long long)(row0 + sr0) * g.lda + sc0;
    const u16* pa1 = g.A + (long long)(row0 + sr1) * g.lda + sc1;
    const u16* pb0 = g.B + (long long)(col0 + sr0) * g.ldb + sc0;
    const u16* pb1 = g.B + (long long)(col0 + sr1) * g.ldb + sc1;

    const int wr = wave >> 1, wc = wave & 1;
    const int fr = lane & 15;
    const int kk = (lane >> 4) * 8;

    f32x4 acc[4][4];
    #pragma unroll
    for (int m = 0; m < 4; ++m)
        #pragma unroll
        for (int n = 0; n < 4; ++n) {
            f32x4 z = {0.f, 0.f, 0.f, 0.f};
            acc[m][n] = z;
        }

    #define STAGE(buf, k0) do { \
        gload16(pa0 + (k0), &lA[buf][(wave * 64) * 8]); \
        gload16(pa1 + (k0), &lA[buf][2048 + (wave * 64) * 8]); \
        gload16(pb0 + (k0), &lB[buf][(wave * 64) * 8]); \
        gload16(pb1 + (k0), &lB[buf][2048 + (wave * 64) * 8]); \
    } while (0)

    STAGE(0, 0);
    __syncthreads();
    int cur = 0;
    for (int k0 = 0; k0 < P.K; k0 += BK) {
        if (k0 + BK < P.K) STAGE(cur ^ 1, k0 + BK);     // issue-early prefetch
        bf16x8 af[4], bfv[4];
        #pragma unroll
        for (int m = 0; m < 4; ++m)
            af[m] = *(const bf16x8*)&lA[cur][(wr * 64 + m * 16 + fr) * BK + kk];
        #pragma unroll
        for (int n = 0; n < 4; ++n)
            bfv[n] = *(const bf16x8*)&lB[cur][(wc * 64 + n * 16 + fr) * BK + kk];
        #pragma unroll
        for (int m = 0; m < 4; ++m)
            #pragma unroll
            for (int n = 0; n < 4; ++n)
                acc[m][n] = __builtin_amdgcn_mfma_f32_16x16x32_bf16(af[m], bfv[n], acc[m][n], 0, 0, 0);
        __syncthreads();       // drains vmcnt(0): next buffer ready
        cur ^= 1;
    }
    #undef STAGE

    // epilogue. C/D layout: col=lane&15, row=(lane>>4)*4+j
    const int orow = row0 + wr * 64;
    const int ocol = col0 + wc * 64;
    const int g4 = (lane >> 4) * 4;
    float bcol[4];
    #pragma unroll
    for (int n = 0; n < 4; ++n)
        bcol[n] = g.bias ? g.bias[ocol + n * 16 + fr] : 0.f;

    #pragma unroll
    for (int m = 0; m < 4; ++m) {
        #pragma unroll
        for (int j = 0; j < 4; ++j) {
            const int r = orow + m * 16 + g4 + j;
            long long ro = 0;
            if (g.resid) {
                unsigned q = (unsigned)r / (unsigned)g.rgrp;
                unsigned rem = (unsigned)r - q * (unsigned)g.rgrp;
                ro = (long long)q * g.rgA + (long long)rem * g.ldr + g.rgoff;
            }
            const long long crow = (long long)r * g.ldc;
            #pragma unroll
            for (int n = 0; n < 4; ++n) {
                const int c = ocol + n * 16 + fr;
                float v = acc[m][n][j] * g.scale + bcol[n];
                if (g.resid) v += g.resid[ro + c];
                if (g.Cb) g.Cb[crow + c] = f2b(v);
                else      g.Cf[crow + c] = v;
            }
        }
    }
}

// ---------------------------------------------------------------------------
// Fused attention core (unchanged from round 3 — verified): per block = one
// z=(b,h), one 128-row q-tile. Pass A: online m/l via S^T=K@Q^T; pass B:
// recompute S=Q@K^T, write normalized attn f32 (phase 1), P->LDS, PV MFMA.
// ---------------------------------------------------------------------------
template <bool WATTN>
__global__ __launch_bounds__(256, 2) void fused_attn(
    const u16* __restrict__ Q, const u16* __restrict__ K, const u16* __restrict__ Vt,
    float* __restrict__ attn, u16* __restrict__ O,
    int Lq, int Lk, int ldq, int ldk, int ldo)
{
    __shared__ __align__(16) u16 lQP[128 * 96];
    __shared__ __align__(16) u16 lKt[64 * 96];
    __shared__ __align__(16) u16 lVt[96 * 64];
    __shared__ float lM2[2][128], lL2[2][128];

    const int tid = threadIdx.x, wave = tid >> 6, lane = tid & 63;
    const int fr = lane & 15, g = lane >> 4;
    const int wr = wave >> 1, wc = wave & 1;
    const int z = blockIdx.y, b = z >> 3, h = z & 7;
    const int q0 = blockIdx.x * 128;
    const int nt = Lk >> 6;

    const u16* Qz = Q + (long long)b * Lq * ldq + h * 96;
    const u16* Kz = K + (long long)b * Lk * ldk + h * 96;
    const u16* Vz = Vt + (long long)z * 96 * Lk;
    u16* Oz = O + (long long)b * Lq * ldo + h * 96;
    float* Az = attn + (long long)z * Lq * Lk;

    const u16* qsrc[6];
    #pragma unroll
    for (int t = 0; t < 6; ++t) {
        int u = t * 256 + tid;
        int r = u / 12, cu = u % 12;
        int qr = q0 + r; if (qr > Lq - 1) qr = Lq - 1;
        qsrc[t] = Qz + (long long)qr * ldq + cu * 8;
    }
    const u16* ksrc[3];
    #pragma unroll
    for (int t = 0; t < 3; ++t) {
        int u = t * 256 + tid;
        int r = u / 12, cu = u % 12;
        ksrc[t] = Kz + (long long)r * ldk + cu * 8;
    }
    const u16* vsrc[3];
    #pragma unroll
    for (int t = 0; t < 3; ++t) {
        int u = t * 256 + tid;
        int d = u >> 3, uu = u & 7;
        vsrc[t] = Vz + (long long)d * Lk + ((uu ^ (d & 7)) * 8);
    }
    const long long kstep = 64LL * ldk;

    #define DQ(t) ((char*)lQP + ((t) * 256 + wave * 64) * 16)
    #define DK(t) ((char*)lKt + ((t) * 256 + wave * 64) * 16)
    #define DV(t) ((char*)lVt + ((t) * 256 + wave * 64) * 16)

    #pragma unroll
    for (int t = 0; t < 6; ++t) gload16(qsrc[t], DQ(t));
    #pragma unroll
    for (int t = 0; t < 3; ++t) gload16(ksrc[t], DK(t));
    __syncthreads();

    bf16x8 qf[4][3];
    #pragma unroll
    for (int m = 0; m < 4; ++m)
        #pragma unroll
        for (int ks = 0; ks < 3; ++ks)
            qf[m][ks] = *(const bf16x8*)((const char*)lQP + (wr * 64 + m * 16 + fr) * 192 + ks * 64 + g * 16);

    float m_run[4], l_run[4];
    #pragma unroll
    for (int i = 0; i < 4; ++i) { m_run[i] = -1e30f; l_run[i] = 0.f; }

    for (int i = 0; i < nt; ++i) {
        bf16x8 kf[2][3];
        #pragma unroll
        for (int mk = 0; mk < 2; ++mk)
            #pragma unroll
            for (int ks = 0; ks < 3; ++ks)
                kf[mk][ks] = *(const bf16x8*)((const char*)lKt + (wc * 32 + mk * 16 + fr) * 192 + ks * 64 + g * 16);
        f32x4 sa[2][4];
        #pragma unroll
        for (int mk = 0; mk < 2; ++mk)
            #pragma unroll
            for (int nq = 0; nq < 4; ++nq) {
                f32x4 zz = {0.f, 0.f, 0.f, 0.f};
                sa[mk][nq] = zz;
            }
        #pragma unroll
        for (int ks = 0; ks < 3; ++ks)
            #pragma unroll
            for (int mk = 0; mk < 2; ++mk)
                #pragma unroll
                for (int nq = 0; nq < 4; ++nq)
                    sa[mk][nq] = __builtin_amdgcn_mfma_f32_16x16x32_bf16(kf[mk][ks], qf[nq][ks], sa[mk][nq], 0, 0, 0);
        #pragma unroll
        for (int nq = 0; nq < 4; ++nq) {
            float tmx = -1e30f;
            #pragma unroll
            for (int mk = 0; mk < 2; ++mk)
                #pragma unroll
                for (int j = 0; j < 4; ++j)
                    tmx = fmaxf(tmx, sa[mk][nq][j]);
            tmx = fmaxf(tmx, __shfl_xor(tmx, 16));
            tmx = fmaxf(tmx, __shfl_xor(tmx, 32));
            const float mnew = fmaxf(m_run[nq], tmx);
            float ts = 0.f;
            #pragma unroll
            for (int mk = 0; mk < 2; ++mk)
                #pragma unroll
                for (int j = 0; j < 4; ++j)
                    ts += __expf(sa[mk][nq][j] - mnew);
            ts += __shfl_xor(ts, 16);
            ts += __shfl_xor(ts, 32);
            l_run[nq] = l_run[nq] * __expf(m_run[nq] - mnew) + ts;
            m_run[nq] = mnew;
        }
        __syncthreads();
        if (i + 1 < nt) {
            #pragma unroll
            for (int t = 0; t < 3; ++t) { ksrc[t] += kstep; gload16(ksrc[t], DK(t)); }
        }
        __syncthreads();
    }

    if (g == 0) {
        #pragma unroll
        for (int nq = 0; nq < 4; ++nq) {
            lM2[wc][wr * 64 + nq * 16 + fr] = m_run[nq];
            lL2[wc][wr * 64 + nq * 16 + fr] = l_run[nq];
        }
    }
    #pragma unroll
    for (int t = 0; t < 3; ++t) ksrc[t] -= (long long)(nt - 1) * kstep;
    #pragma unroll
    for (int t = 0; t < 3; ++t) gload16(ksrc[t], DK(t));
    #pragma unroll
    for (int t = 0; t < 3; ++t) gload16(vsrc[t], DV(t));
    __syncthreads();

    float mrow[16], linv[16];
    #pragma unroll
    for (int m = 0; m < 4; ++m)
        #pragma unroll
        for (int j = 0; j < 4; ++j) {
            const int q = wr * 64 + m * 16 + g * 4 + j;
            const float ma = lM2[0][q], mb = lM2[1][q];
            const float mm = fmaxf(ma, mb);
            const float ll = lL2[0][q] * __expf(ma - mm) + lL2[1][q] * __expf(mb - mm);
            mrow[m * 4 + j] = mm;
            linv[m * 4 + j] = 1.f / ll;
        }

    f32x4 oacc[4][3];
    #pragma unroll
    for (int m = 0; m < 4; ++m)
        #pragma unroll
        for (int nd = 0; nd < 3; ++nd) {
            f32x4 zz = {0.f, 0.f, 0.f, 0.f};
            oacc[m][nd] = zz;
        }

    for (int i = 0; i < nt; ++i) {
        const int k0 = i * 64;
        bf16x8 kf[2][3];
        #pragma unroll
        for (int n = 0; n < 2; ++n)
            #pragma unroll
            for (int ks = 0; ks < 3; ++ks)
                kf[n][ks] = *(const bf16x8*)((const char*)lKt + (wc * 32 + n * 16 + fr) * 192 + ks * 64 + g * 16);
        f32x4 ss[4][2];
        #pragma unroll
        for (int m = 0; m < 4; ++m)
            #pragma unroll
            for (int n = 0; n < 2; ++n) {
                f32x4 zz = {0.f, 0.f, 0.f, 0.f};
                ss[m][n] = zz;
            }
        #pragma unroll
        for (int ks = 0; ks < 3; ++ks)
            #pragma unroll
            for (int m = 0; m < 4; ++m)
                #pragma unroll
                for (int n = 0; n < 2; ++n)
                    ss[m][n] = __builtin_amdgcn_mfma_f32_16x16x32_bf16(qf[m][ks], kf[n][ks], ss[m][n], 0, 0, 0);
        __syncthreads();
        if (i + 1 < nt) {
            #pragma unroll
            for (int t = 0; t < 3; ++t) { ksrc[t] += kstep; gload16(ksrc[t], DK(t)); }
        }
        #pragma unroll
        for (int m = 0; m < 4; ++m)
            #pragma unroll
            for (int n = 0; n < 2; ++n)
                #pragma unroll
                for (int j = 0; j < 4; ++j) {
                    const float p = __expf(ss[m][n][j] - mrow[m * 4 + j]) * linv[m * 4 + j];
                    const int q = wr * 64 + m * 16 + g * 4 + j;
                    const int k = wc * 32 + n * 16 + fr;
                    if (WATTN) Az[(long long)(q0 + q) * Lk + k0 + k] = p;
                    *(u16*)((char*)lQP + q * 144 + k * 2) = f2b(p);
                }
        __syncthreads();
        #pragma unroll
        for (int ks = 0; ks < 2; ++ks) {
            bf16x8 vf[3], pf[4];
            #pragma unroll
            for (int nd = 0; nd < 3; ++nd) {
                const int row = wc * 48 + nd * 16 + fr;
                vf[nd] = *(const bf16x8*)((const char*)lVt + row * 128 + (((ks * 4 + g) ^ (row & 7)) * 16));
            }
            #pragma unroll
            for (int m = 0; m < 4; ++m)
                pf[m] = *(const bf16x8*)((const char*)lQP + (wr * 64 + m * 16 + fr) * 144 + ks * 64 + g * 16);
            #pragma unroll
            for (int m = 0; m < 4; ++m)
                #pragma unroll
                for (int nd = 0; nd < 3; ++nd)
                    oacc[m][nd] = __builtin_amdgcn_mfma_f32_16x16x32_bf16(pf[m], vf[nd], oacc[m][nd], 0, 0, 0);
        }
        __syncthreads();
        if (i + 1 < nt) {
            #pragma unroll
            for (int t = 0; t < 3; ++t) { vsrc[t] += 64; gload16(vsrc[t], DV(t)); }
        }
    }

    #pragma unroll
    for (int m = 0; m < 4; ++m)
        #pragma unroll
        for (int j = 0; j < 4; ++j) {
            const int q = q0 + wr * 64 + m * 16 + g * 4 + j;
            if (q < Lq) {
                #pragma unroll
                for (int nd = 0; nd < 3; ++nd) {
                    const int c = wc * 48 + nd * 16 + fr;
                    Oz[(long long)q * ldo + c] = f2b(oacc[m][nd][j]);
                }
            }
        }
    #undef DQ
    #undef DK
    #undef DV
}

// ---------------------------------------------------------------------------
__global__ __launch_bounds__(256) void transpose_v(
    const u16* __restrict__ V, u16* __restrict__ Vt, int L, int ldv)
{
    __shared__ unsigned int t[64 * 97];
    const int z = blockIdx.y;
    const int b = z >> 3, h = z & 7;
    const int l0 = blockIdx.x * 64;
    const int tid = threadIdx.x;
    for (int i = 0; i < 24; ++i) {
        const int idx = tid + i * 256;
        const int l = idx / 96, d = idx % 96;
        t[l * 97 + d] = V[((long long)(b * L + l0 + l)) * ldv + h * 96 + d];
    }
    __syncthreads();
    for (int i = 0; i < 24; ++i) {
        const int idx = tid + i * 256;
        const int d = idx / 64, l = idx % 64;
        Vt[((long long)z * 96 + d) * L + l0 + l] = (u16)t[l * 97 + d];
    }
}

// ---------------------------------------------------------------------------
__global__ __launch_bounds__(256) void ln_k(
    const float* __restrict__ X, const float* __restrict__ g, const float* __restrict__ b,
    float* __restrict__ outF, u16* __restrict__ outB,
    int rows, int grp, long long gA, long long goff, int ldo)
{
    const int wave = threadIdx.x >> 6, lane = threadIdx.x & 63;
    const int row = blockIdx.x * 4 + wave;
    if (row >= rows) return;
    const float* x = X + (long long)row * 768;
    float v[12], s = 0.f, sq = 0.f;
    #pragma unroll
    for (int i = 0; i < 12; ++i) { v[i] = x[lane + 64 * i]; s += v[i]; sq += v[i] * v[i]; }
    #pragma unroll
    for (int o = 32; o; o >>= 1) { s += __shfl_xor(s, o); sq += __shfl_xor(sq, o); }
    const float mu = s * (1.f / 768.f);
    const float var = sq * (1.f / 768.f) - mu * mu;
    const float inv = rsqrtf(var + 1e-5f);
    const long long ob = (long long)(row / grp) * gA + (long long)(row % grp) * ldo + goff;
    #pragma unroll
    for (int i = 0; i < 12; ++i) {
        const int c = lane + 64 * i;
        const float y = (v[i] - mu) * inv * g[c] + b[c];
        outF[ob + c] = y;
        if (outB) outB[(long long)row * 768 + c] = f2b(y);
    }
}

__global__ __launch_bounds__(256) void conv_f2b(
    const float4* __restrict__ in, u16* __restrict__ out, long long n4)
{
    long long i = (long long)blockIdx.x * 256 + threadIdx.x;
    const long long stride = (long long)gridDim.x * 256;
    for (; i < n4; i += stride) {
        const float4 f = in[i];
        ushort4 u;
        u.x = f2b(f.x); u.y = f2b(f.y); u.z = f2b(f.z); u.w = f2b(f.w);
        ((ushort4*)out)[i] = u;
    }
}

// all 4 weight matrices (w1in|w1out|w2in|w2out) in one launch
__global__ __launch_bounds__(256) void conv_w4(
    const float4* __restrict__ a, const float4* __restrict__ b,
    const float4* __restrict__ c, const float4* __restrict__ d,
    u16* __restrict__ oa, u16* __restrict__ ob,
    u16* __restrict__ oc, u16* __restrict__ od)
{
    const long long n1 = 442368, n2 = 589824, n3 = 1032192, n4 = 1179648;
    long long i = (long long)blockIdx.x * 256 + threadIdx.x;
    const long long stride = (long long)gridDim.x * 256;
    for (; i < n4; i += stride) {
        const float4* src; u16* dst; long long k;
        if (i < n1)      { src = a; dst = oa; k = i; }
        else if (i < n2) { src = b; dst = ob; k = i - n1; }
        else if (i < n3) { src = c; dst = oc; k = i - n2; }
        else             { src = d; dst = od; k = i - n3; }
        const float4 f = src[k];
        ushort4 u;
        u.x = f2b(f.x); u.y = f2b(f.y); u.z = f2b(f.z); u.w = f2b(f.w);
        ((ushort4*)dst)[k] = u;
    }
}

__global__ __launch_bounds__(256) void conv_patch(
    const float* __restrict__ img, u16* __restrict__ out)
{
    long long i = (long long)blockIdx.x * 256 + threadIdx.x;
    const long long n4 = 18432LL * 192;
    const long long stride = (long long)gridDim.x * 256;
    for (; i < n4; i += stride) {
        const long long r = i / 192; const int c4 = (int)(i % 192);
        const long long sr = (r / 576) * 577 + 1 + (r % 576);
        const float4 f = ((const float4*)img)[sr * 192 + c4];
        ushort4 u;
        u.x = f2b(f.x); u.y = f2b(f.y); u.z = f2b(f.z); u.w = f2b(f.w);
        ((ushort4*)out)[i] = u;
    }
}

__global__ __launch_bounds__(256) void cls_copy(
    const float* __restrict__ img, float* __restrict__ out)
{
    const int i = blockIdx.x * 256 + threadIdx.x;
    if (i < 32 * 768) {
        const int b = i / 768, c = i % 768;
        out[(long long)b * 577 * 768 + c] = img[(long long)b * 577 * 768 + c];
    }
}

// ---------------------------------------------------------------------------
static inline GemmGrp mkgrp(const u16* A, const u16* B, const float* bias,
    const float* resid, float* Cf, u16* Cb, int M, int N, int lda, int ldb,
    int ldc, float scale, int rgrp, long long rgA, long long rgoff, int ldr)
{
    GemmGrp g;
    g.A = A; g.B = B; g.bias = bias; g.resid = resid; g.Cf = Cf; g.Cb = Cb;
    g.M = M; g.N = N; g.lda = lda; g.ldb = ldb; g.ldc = ldc;
    g.scale = scale; g.rgrp = rgrp; g.rgA = rgA; g.rgoff = rgoff; g.ldr = ldr;
    return g;
}

static inline void launch_grp(hipStream_t s, const GemmGrp* gs, int ng, int K)
{
    G3 P;
    P.start[0] = 0;
    for (int i = 0; i < 3; ++i) {
        const GemmGrp& src = gs[i < ng ? i : ng - 1];
        P.g[i] = src;
        const int nb = (i < ng) ? (src.M / BM) * (src.N / BN) : 0;
        P.start[i + 1] = P.start[i] + nb;
    }
    P.K = K;
    gemm_grp<<<dim3((unsigned)P.start[3]), dim3(256), 0, s>>>(P);
}

extern "C" void kernel_launch(void* const* d_in, const int* in_sizes, int n_in,
                              void* d_out, int out_size, void* d_ws, size_t ws_size,
                              hipStream_t stream)
{
    (void)in_sizes; (void)n_in; (void)out_size; (void)ws_size;
    const float* img   = (const float*)d_in[0];
    const float* tac   = (const float*)d_in[1];
    const float* w1in  = (const float*)d_in[2];
    const float* b1in  = (const float*)d_in[3];
    const float* w1out = (const float*)d_in[4];
    const float* b1out = (const float*)d_in[5];
    const float* w2in  = (const float*)d_in[6];
    const float* b2in  = (const float*)d_in[7];
    const float* w2out = (const float*)d_in[8];
    const float* b2out = (const float*)d_in[9];
    const float* lng1  = (const float*)d_in[10];
    const float* lnb1  = (const float*)d_in[11];
    const float* lng2  = (const float*)d_in[12];
    const float* lnb2  = (const float*)d_in[13];
    float* out = (float*)d_out;

    const long long o_tac  = 32LL * 577 * 768;
    const long long o_attn = o_tac + 32LL * 256 * 768;
    const float qscale = 1.0f / sqrtf(96.0f);

    // ---- workspace arena (ws ~931 MB; total used ~350 MB, no overlays) ----
    u16* p = (u16*)d_ws;
    u16* tact_bf    = p; p += 8192LL * 768;
    u16* patch_bf   = p; p += 18432LL * 768;
    u16* w1in_bf    = p; p += 2304LL * 768;
    u16* w1out_bf   = p; p += 768LL * 768;
    u16* w2in_bf    = p; p += 2304LL * 768;
    u16* w2out_bf   = p; p += 768LL * 768;
    u16* tactnew_bf = p; p += 8192LL * 768;
    u16* Q1  = p; p += 8192LL * 768;
    u16* KV1 = p; p += 18432LL * 1536;
    u16* Vt1 = p; p += 256LL * 96 * 576;
    u16* AO1 = p; p += 8192LL * 768;
    u16* Q2  = p; p += 18432LL * 768;
    u16* KV2 = p; p += 8192LL * 1536;
    u16* Vt2 = p; p += 256LL * 96 * 256;
    u16* AO2 = p; p += 18432LL * 768;
    float* O1s = (float*)p; p += 2LL * 8192 * 768;
    float* O2s = (float*)p; p += 2LL * 18432 * 768;

    // ---- f32 -> bf16 conversions ----
    conv_f2b<<<1024, 256, 0, stream>>>((const float4*)tac, tact_bf, 8192LL * 192);
    conv_patch<<<1024, 256, 0, stream>>>(img, patch_bf);
    conv_w4<<<1024, 256, 0, stream>>>(
        (const float4*)w1in, (const float4*)w1out, (const float4*)w2in, (const float4*)w2out,
        w1in_bf, w1out_bf, w2in_bf, w2out_bf);
    cls_copy<<<96, 256, 0, stream>>>(img, out);

    // ---- merged projections: Q1 + KV1 + Q2 (independent; 2976 blocks) ----
    {
        GemmGrp gs[3] = {
            mkgrp(tact_bf,  w1in_bf,              b1in,       nullptr, nullptr, Q1,
                  8192, 768, 768, 768, 768, qscale, 1, 0, 0, 0),
            mkgrp(patch_bf, w1in_bf + 768LL*768,  b1in + 768, nullptr, nullptr, KV1,
                  18432, 1536, 768, 768, 1536, 1.0f, 1, 0, 0, 0),
            mkgrp(patch_bf, w2in_bf,              b2in,       nullptr, nullptr, Q2,
                  18432, 768, 768, 768, 768, qscale, 1, 0, 0, 0)
        };
        launch_grp(stream, gs, 3, 768);
    }

    // ================= phase 1: t2i MHA (q=tactile, kv=patch) =================
    transpose_v<<<dim3(9, 256), 256, 0, stream>>>(KV1 + 768, Vt1, 576, 1536);
    fused_attn<true><<<dim3(2, 256), 256, 0, stream>>>(
        Q1, KV1, Vt1, out + o_attn, AO1, 256, 576, 768, 1536, 768);
    {
        GemmGrp g = mkgrp(AO1, w1out_bf, b1out, tac, O1s, nullptr,
                          8192, 768, 768, 768, 768, 1.0f, 1, 768, 0, 0);
        launch_grp(stream, &g, 1, 768);
    }
    ln_k<<<8192 / 4, 256, 0, stream>>>(O1s, lng1, lnb1, out + o_tac, tactnew_bf,
        8192, 8192, 0, 0, 768);

    // ================= phase 2: i2t MHA (q=patch, kv=tactile_new) =============
    {
        GemmGrp g = mkgrp(tactnew_bf, w2in_bf + 768LL*768, b2in + 768, nullptr,
                          nullptr, KV2, 8192, 1536, 768, 768, 1536, 1.0f, 1, 0, 0, 0);
        launch_grp(stream, &g, 1, 768);
    }
    transpose_v<<<dim3(4, 256), 256, 0, stream>>>(KV2 + 768, Vt2, 256, 1536);
    fused_attn<false><<<dim3(5, 256), 256, 0, stream>>>(
        Q2, KV2, Vt2, nullptr, AO2, 576, 256, 768, 1536, 768);
    {
        GemmGrp g = mkgrp(AO2, w2out_bf, b2out, img, O2s, nullptr,
                          18432, 768, 768, 768, 768, 1.0f, 576, 577LL * 768, 768, 768);
        launch_grp(stream, &g, 1, 768);
    }
    ln_k<<<18432 / 4, 256, 0, stream>>>(O2s, lng2, lnb2, out, nullptr,
        18432, 576, 577LL * 768, 768, 768);
}

// Round 7
// 763.778 us; speedup vs baseline: 1.5591x; 1.0014x over previous
//
#include <hip/hip_runtime.h>
#include <stdint.h>
#include <math.h>

typedef unsigned short u16;
typedef __attribute__((ext_vector_type(8))) short bf16x8;   // 8 bf16 in 4 VGPRs
typedef __attribute__((ext_vector_type(4))) float f32x4;

__device__ __forceinline__ u16 f2b(float f) {
    unsigned u = __float_as_uint(f);
    u = (u + 0x7FFFu + ((u >> 16) & 1u)) >> 16;   // RNE
    return (u16)u;
}

// async global->LDS, 16B per lane. lds dest = wave-uniform base + lane*16.
__device__ __forceinline__ void gload16(const void* g, void* lds) {
    __builtin_amdgcn_global_load_lds(
        (const __attribute__((address_space(1))) unsigned int*)(uintptr_t)g,
        (__attribute__((address_space(3))) unsigned int*)(unsigned int)(uintptr_t)lds,
        16, 0, 0);
}

// ---------------------------------------------------------------------------
// Grouped GEMM (verified round 6): up to 3 independent C = A @ B^T in one
// launch. 128x128 tile, BK=32, double-buffered LDS, XCD bijective swizzle.
// ---------------------------------------------------------------------------
#define BM 128
#define BN 128
#define BK 32

struct GemmGrp {
    const u16* A; const u16* B; const float* bias; const float* resid;
    float* Cf; u16* Cb;
    int M, N, lda, ldb, ldc;
    float scale;
    int rgrp; long long rgA, rgoff; int ldr;
};
struct G3 { GemmGrp g[3]; int start[4]; int K; };

__global__ __launch_bounds__(256) void gemm_grp(G3 P)
{
    __shared__ __align__(16) u16 lA[2][BM * BK];
    __shared__ __align__(16) u16 lB[2][BN * BK];

    const int tid = threadIdx.x;
    const int wave = tid >> 6;
    const int lane = tid & 63;

    const int ntot = P.start[3];
    int L = blockIdx.x;
    if ((ntot & 7) == 0) L = (L & 7) * (ntot >> 3) + (L >> 3);

    const int gi = (L >= P.start[1]) + (L >= P.start[2]);
    GemmGrp g;
    if (gi == 0) g = P.g[0]; else if (gi == 1) g = P.g[1]; else g = P.g[2];
    const int t = L - P.start[gi];

    const int tilesN = g.N / BN;
    const int tm = t / tilesN;
    const int tn = t % tilesN;
    const int row0 = tm * BM;
    const int col0 = tn * BN;

    const int f0 = tid * 8;
    const int f1 = (256 + tid) * 8;
    const int sr0 = f0 >> 5, sc0 = f0 & 31;
    const int sr1 = f1 >> 5, sc1 = f1 & 31;

    const u16* pa0 = g.A + (long long)(row0 + sr0) * g.lda + sc0;
    const u16* pa1 = g.A + (long long)(row0 + sr1) * g.lda + sc1;
    const u16* pb0 = g.B + (long long)(col0 + sr0) * g.ldb + sc0;
    const u16* pb1 = g.B + (long long)(col0 + sr1) * g.ldb + sc1;

    const int wr = wave >> 1, wc = wave & 1;
    const int fr = lane & 15;
    const int kk = (lane >> 4) * 8;

    f32x4 acc[4][4];
    #pragma unroll
    for (int m = 0; m < 4; ++m)
        #pragma unroll
        for (int n = 0; n < 4; ++n) {
            f32x4 z = {0.f, 0.f, 0.f, 0.f};
            acc[m][n] = z;
        }

    #define STAGE(buf, k0) do { \
        gload16(pa0 + (k0), &lA[buf][(wave * 64) * 8]); \
        gload16(pa1 + (k0), &lA[buf][2048 + (wave * 64) * 8]); \
        gload16(pb0 + (k0), &lB[buf][(wave * 64) * 8]); \
        gload16(pb1 + (k0), &lB[buf][2048 + (wave * 64) * 8]); \
    } while (0)

    STAGE(0, 0);
    __syncthreads();
    int cur = 0;
    for (int k0 = 0; k0 < P.K; k0 += BK) {
        if (k0 + BK < P.K) STAGE(cur ^ 1, k0 + BK);
        bf16x8 af[4], bfv[4];
        #pragma unroll
        for (int m = 0; m < 4; ++m)
            af[m] = *(const bf16x8*)&lA[cur][(wr * 64 + m * 16 + fr) * BK + kk];
        #pragma unroll
        for (int n = 0; n < 4; ++n)
            bfv[n] = *(const bf16x8*)&lB[cur][(wc * 64 + n * 16 + fr) * BK + kk];
        #pragma unroll
        for (int m = 0; m < 4; ++m)
            #pragma unroll
            for (int n = 0; n < 4; ++n)
                acc[m][n] = __builtin_amdgcn_mfma_f32_16x16x32_bf16(af[m], bfv[n], acc[m][n], 0, 0, 0);
        __syncthreads();
        cur ^= 1;
    }
    #undef STAGE

    const int orow = row0 + wr * 64;
    const int ocol = col0 + wc * 64;
    const int g4 = (lane >> 4) * 4;
    float bcol[4];
    #pragma unroll
    for (int n = 0; n < 4; ++n)
        bcol[n] = g.bias ? g.bias[ocol + n * 16 + fr] : 0.f;

    #pragma unroll
    for (int m = 0; m < 4; ++m) {
        #pragma unroll
        for (int j = 0; j < 4; ++j) {
            const int r = orow + m * 16 + g4 + j;
            long long ro = 0;
            if (g.resid) {
                unsigned q = (unsigned)r / (unsigned)g.rgrp;
                unsigned rem = (unsigned)r - q * (unsigned)g.rgrp;
                ro = (long long)q * g.rgA + (long long)rem * g.ldr + g.rgoff;
            }
            const long long crow = (long long)r * g.ldc;
            #pragma unroll
            for (int n = 0; n < 4; ++n) {
                const int c = ocol + n * 16 + fr;
                float v = acc[m][n][j] * g.scale + bcol[n];
                if (g.resid) v += g.resid[ro + c];
                if (g.Cb) g.Cb[crow + c] = f2b(v);
                else      g.Cf[crow + c] = v;
            }
        }
    }
}

// ---------------------------------------------------------------------------
// Fused attention core, round 7: double-buffered K (pass A) and K+V (pass B)
// with ISSUE-EARLY staging (stage at top of iter, drain at the barrier AFTER
// compute -> HBM latency hides under MFMA/softmax). Pass A: 1 barrier/iter
// (was 2); pass B: 2 barriers/iter (was 3). setprio around MFMA clusters.
// LDS = 24.6(QP) + 24.6(K x2) + 24.6(V x2) + 2 = 75.8 KB -> 2 blocks/CU.
// ---------------------------------------------------------------------------
template <bool WATTN>
__global__ __launch_bounds__(256, 2) void fused_attn(
    const u16* __restrict__ Q, const u16* __restrict__ K, const u16* __restrict__ Vt,
    float* __restrict__ attn, u16* __restrict__ O,
    int Lq, int Lk, int ldq, int ldk, int ldo)
{
    __shared__ __align__(16) u16 lQP[128 * 96];      // Q[128][96] then P[128][72] overlay
    __shared__ __align__(16) u16 lKt[2][64 * 96];    // K-tile dbuf
    __shared__ __align__(16) u16 lVt[2][96 * 64];    // V-tile dbuf (XOR-swizzled)
    __shared__ float lM2[2][128], lL2[2][128];

    const int tid = threadIdx.x, wave = tid >> 6, lane = tid & 63;
    const int fr = lane & 15, g = lane >> 4;
    const int wr = wave >> 1, wc = wave & 1;
    const int z = blockIdx.y, b = z >> 3, h = z & 7;
    const int q0 = blockIdx.x * 128;
    const int nt = Lk >> 6;

    const u16* Qz = Q + (long long)b * Lq * ldq + h * 96;
    const u16* Kz = K + (long long)b * Lk * ldk + h * 96;
    const u16* Vz = Vt + (long long)z * 96 * Lk;
    u16* Oz = O + (long long)b * Lq * ldo + h * 96;
    float* Az = attn + (long long)z * Lq * Lk;

    const u16* qsrc[6];
    #pragma unroll
    for (int t = 0; t < 6; ++t) {
        int u = t * 256 + tid;
        int r = u / 12, cu = u % 12;
        int qr = q0 + r; if (qr > Lq - 1) qr = Lq - 1;
        qsrc[t] = Qz + (long long)qr * ldq + cu * 8;
    }
    const u16* ksrc[3];
    #pragma unroll
    for (int t = 0; t < 3; ++t) {
        int u = t * 256 + tid;
        int r = u / 12, cu = u % 12;
        ksrc[t] = Kz + (long long)r * ldk + cu * 8;
    }
    const u16* vsrc[3];
    #pragma unroll
    for (int t = 0; t < 3; ++t) {
        int u = t * 256 + tid;
        int d = u >> 3, uu = u & 7;
        vsrc[t] = Vz + (long long)d * Lk + ((uu ^ (d & 7)) * 8);  // pre-swizzled src
    }
    const long long kstep = 64LL * ldk;

    #define DQ(t)    ((char*)lQP + ((t) * 256 + wave * 64) * 16)
    #define DK(bf,t) ((char*)lKt[bf] + ((t) * 256 + wave * 64) * 16)
    #define DV(bf,t) ((char*)lVt[bf] + ((t) * 256 + wave * 64) * 16)

    // prologue: stage Q (once) and K[0]
    #pragma unroll
    for (int t = 0; t < 6; ++t) gload16(qsrc[t], DQ(t));
    #pragma unroll
    for (int t = 0; t < 3; ++t) gload16(ksrc[t], DK(0, t));
    __syncthreads();

    // Q fragments -> regs (held for both passes); frees lQP for P
    bf16x8 qf[4][3];
    #pragma unroll
    for (int m = 0; m < 4; ++m)
        #pragma unroll
        for (int ks = 0; ks < 3; ++ks)
            qf[m][ks] = *(const bf16x8*)((const char*)lQP + (wr * 64 + m * 16 + fr) * 192 + ks * 64 + g * 16);

    // ---------------- pass A: online m,l (1 barrier/iter, issue-early) -------
    float m_run[4], l_run[4];
    #pragma unroll
    for (int i = 0; i < 4; ++i) { m_run[i] = -1e30f; l_run[i] = 0.f; }

    int buf = 0;
    for (int i = 0; i < nt; ++i) {
        if (i + 1 < nt) {
            #pragma unroll
            for (int t = 0; t < 3; ++t) { ksrc[t] += kstep; gload16(ksrc[t], DK(buf ^ 1, t)); }
        }
        bf16x8 kf[2][3];
        #pragma unroll
        for (int mk = 0; mk < 2; ++mk)
            #pragma unroll
            for (int ks = 0; ks < 3; ++ks)
                kf[mk][ks] = *(const bf16x8*)((const char*)lKt[buf] + (wc * 32 + mk * 16 + fr) * 192 + ks * 64 + g * 16);
        f32x4 sa[2][4];
        #pragma unroll
        for (int mk = 0; mk < 2; ++mk)
            #pragma unroll
            for (int nq = 0; nq < 4; ++nq) {
                f32x4 zz = {0.f, 0.f, 0.f, 0.f};
                sa[mk][nq] = zz;
            }
        __builtin_amdgcn_s_setprio(1);
        #pragma unroll
        for (int ks = 0; ks < 3; ++ks)
            #pragma unroll
            for (int mk = 0; mk < 2; ++mk)
                #pragma unroll
                for (int nq = 0; nq < 4; ++nq)
                    sa[mk][nq] = __builtin_amdgcn_mfma_f32_16x16x32_bf16(kf[mk][ks], qf[nq][ks], sa[mk][nq], 0, 0, 0);
        __builtin_amdgcn_s_setprio(0);
        #pragma unroll
        for (int nq = 0; nq < 4; ++nq) {
            float tmx = -1e30f;
            #pragma unroll
            for (int mk = 0; mk < 2; ++mk)
                #pragma unroll
                for (int j = 0; j < 4; ++j)
                    tmx = fmaxf(tmx, sa[mk][nq][j]);
            tmx = fmaxf(tmx, __shfl_xor(tmx, 16));
            tmx = fmaxf(tmx, __shfl_xor(tmx, 32));
            const float mnew = fmaxf(m_run[nq], tmx);
            float ts = 0.f;
            #pragma unroll
            for (int mk = 0; mk < 2; ++mk)
                #pragma unroll
                for (int j = 0; j < 4; ++j)
                    ts += __expf(sa[mk][nq][j] - mnew);
            ts += __shfl_xor(ts, 16);
            ts += __shfl_xor(ts, 32);
            l_run[nq] = l_run[nq] * __expf(m_run[nq] - mnew) + ts;
            m_run[nq] = mnew;
        }
        __syncthreads();   // drains stage of K[i+1]; all waves done reading lKt[buf]
        buf ^= 1;
    }

    // publish per-half m,l
    if (g == 0) {
        #pragma unroll
        for (int nq = 0; nq < 4; ++nq) {
            lM2[wc][wr * 64 + nq * 16 + fr] = m_run[nq];
            lL2[wc][wr * 64 + nq * 16 + fr] = l_run[nq];
        }
    }
    // pass-B prologue: rewind K; stage K[0] + V[0] into buf 0
    #pragma unroll
    for (int t = 0; t < 3; ++t) ksrc[t] -= (long long)(nt - 1) * kstep;
    #pragma unroll
    for (int t = 0; t < 3; ++t) gload16(ksrc[t], DK(0, t));
    #pragma unroll
    for (int t = 0; t < 3; ++t) gload16(vsrc[t], DV(0, t));
    __syncthreads();   // lM2/lL2 visible; K[0],V[0] ready

    float mrow[16], linv[16];
    #pragma unroll
    for (int m = 0; m < 4; ++m)
        #pragma unroll
        for (int j = 0; j < 4; ++j) {
            const int q = wr * 64 + m * 16 + g * 4 + j;
            const float ma = lM2[0][q], mb = lM2[1][q];
            const float mm = fmaxf(ma, mb);
            const float ll = lL2[0][q] * __expf(ma - mm) + lL2[1][q] * __expf(mb - mm);
            mrow[m * 4 + j] = mm;
            linv[m * 4 + j] = 1.f / ll;
        }

    // ---------------- pass B: S, p -> attn + LDS, PV (2 barriers/iter) -------
    f32x4 oacc[4][3];
    #pragma unroll
    for (int m = 0; m < 4; ++m)
        #pragma unroll
        for (int nd = 0; nd < 3; ++nd) {
            f32x4 zz = {0.f, 0.f, 0.f, 0.f};
            oacc[m][nd] = zz;
        }

    buf = 0;
    for (int i = 0; i < nt; ++i) {
        const int k0 = i * 64;
        if (i + 1 < nt) {
            #pragma unroll
            for (int t = 0; t < 3; ++t) { ksrc[t] += kstep; gload16(ksrc[t], DK(buf ^ 1, t)); }
            #pragma unroll
            for (int t = 0; t < 3; ++t) { vsrc[t] += 64;    gload16(vsrc[t], DV(buf ^ 1, t)); }
        }
        bf16x8 kf[2][3];
        #pragma unroll
        for (int n = 0; n < 2; ++n)
            #pragma unroll
            for (int ks = 0; ks < 3; ++ks)
                kf[n][ks] = *(const bf16x8*)((const char*)lKt[buf] + (wc * 32 + n * 16 + fr) * 192 + ks * 64 + g * 16);
        f32x4 ss[4][2];
        #pragma unroll
        for (int m = 0; m < 4; ++m)
            #pragma unroll
            for (int n = 0; n < 2; ++n) {
                f32x4 zz = {0.f, 0.f, 0.f, 0.f};
                ss[m][n] = zz;
            }
        __builtin_amdgcn_s_setprio(1);
        #pragma unroll
        for (int ks = 0; ks < 3; ++ks)
            #pragma unroll
            for (int m = 0; m < 4; ++m)
                #pragma unroll
                for (int n = 0; n < 2; ++n)
                    ss[m][n] = __builtin_amdgcn_mfma_f32_16x16x32_bf16(qf[m][ks], kf[n][ks], ss[m][n], 0, 0, 0);
        __builtin_amdgcn_s_setprio(0);
        // normalized p: write attn (f32) and P (bf16, LDS rows padded to 72)
        #pragma unroll
        for (int m = 0; m < 4; ++m)
            #pragma unroll
            for (int n = 0; n < 2; ++n)
                #pragma unroll
                for (int j = 0; j < 4; ++j) {
                    const float p = __expf(ss[m][n][j] - mrow[m * 4 + j]) * linv[m * 4 + j];
                    const int q = wr * 64 + m * 16 + g * 4 + j;
                    const int k = wc * 32 + n * 16 + fr;
                    if (WATTN) Az[(long long)(q0 + q) * Lk + k0 + k] = p;
                    *(u16*)((char*)lQP + q * 144 + k * 2) = f2b(p);
                }
        __syncthreads();   // (a) P visible; K[i+1]/V[i+1] stages drained
        __builtin_amdgcn_s_setprio(1);
        #pragma unroll
        for (int ks = 0; ks < 2; ++ks) {
            bf16x8 vf[3], pf[4];
            #pragma unroll
            for (int nd = 0; nd < 3; ++nd) {
                const int row = wc * 48 + nd * 16 + fr;
                vf[nd] = *(const bf16x8*)((const char*)lVt[buf] + row * 128 + (((ks * 4 + g) ^ (row & 7)) * 16));
            }
            #pragma unroll
            for (int m = 0; m < 4; ++m)
                pf[m] = *(const bf16x8*)((const char*)lQP + (wr * 64 + m * 16 + fr) * 144 + ks * 64 + g * 16);
            #pragma unroll
            for (int m = 0; m < 4; ++m)
                #pragma unroll
                for (int nd = 0; nd < 3; ++nd)
                    oacc[m][nd] = __builtin_amdgcn_mfma_f32_16x16x32_bf16(pf[m], vf[nd], oacc[m][nd], 0, 0, 0);
        }
        __builtin_amdgcn_s_setprio(0);
        __syncthreads();   // (b) done reading lQP + lVt[buf] before next overwrite
        buf ^= 1;
    }

    #pragma unroll
    for (int m = 0; m < 4; ++m)
        #pragma unroll
        for (int j = 0; j < 4; ++j) {
            const int q = q0 + wr * 64 + m * 16 + g * 4 + j;
            if (q < Lq) {
                #pragma unroll
                for (int nd = 0; nd < 3; ++nd) {
                    const int c = wc * 48 + nd * 16 + fr;
                    Oz[(long long)q * ldo + c] = f2b(oacc[m][nd][j]);
                }
            }
        }
    #undef DQ
    #undef DK
    #undef DV
}

// ---------------------------------------------------------------------------
__global__ __launch_bounds__(256) void transpose_v(
    const u16* __restrict__ V, u16* __restrict__ Vt, int L, int ldv)
{
    __shared__ unsigned int t[64 * 97];
    const int z = blockIdx.y;
    const int b = z >> 3, h = z & 7;
    const int l0 = blockIdx.x * 64;
    const int tid = threadIdx.x;
    for (int i = 0; i < 24; ++i) {
        const int idx = tid + i * 256;
        const int l = idx / 96, d = idx % 96;
        t[l * 97 + d] = V[((long long)(b * L + l0 + l)) * ldv + h * 96 + d];
    }
    __syncthreads();
    for (int i = 0; i < 24; ++i) {
        const int idx = tid + i * 256;
        const int d = idx / 64, l = idx % 64;
        Vt[((long long)z * 96 + d) * L + l0 + l] = (u16)t[l * 97 + d];
    }
}

// ---------------------------------------------------------------------------
__global__ __launch_bounds__(256) void ln_k(
    const float* __restrict__ X, const float* __restrict__ g, const float* __restrict__ b,
    float* __restrict__ outF, u16* __restrict__ outB,
    int rows, int grp, long long gA, long long goff, int ldo)
{
    const int wave = threadIdx.x >> 6, lane = threadIdx.x & 63;
    const int row = blockIdx.x * 4 + wave;
    if (row >= rows) return;
    const float* x = X + (long long)row * 768;
    float v[12], s = 0.f, sq = 0.f;
    #pragma unroll
    for (int i = 0; i < 12; ++i) { v[i] = x[lane + 64 * i]; s += v[i]; sq += v[i] * v[i]; }
    #pragma unroll
    for (int o = 32; o; o >>= 1) { s += __shfl_xor(s, o); sq += __shfl_xor(sq, o); }
    const float mu = s * (1.f / 768.f);
    const float var = sq * (1.f / 768.f) - mu * mu;
    const float inv = rsqrtf(var + 1e-5f);
    const long long ob = (long long)(row / grp) * gA + (long long)(row % grp) * ldo + goff;
    #pragma unroll
    for (int i = 0; i < 12; ++i) {
        const int c = lane + 64 * i;
        const float y = (v[i] - mu) * inv * g[c] + b[c];
        outF[ob + c] = y;
        if (outB) outB[(long long)row * 768 + c] = f2b(y);
    }
}

__global__ __launch_bounds__(256) void conv_f2b(
    const float4* __restrict__ in, u16* __restrict__ out, long long n4)
{
    long long i = (long long)blockIdx.x * 256 + threadIdx.x;
    const long long stride = (long long)gridDim.x * 256;
    for (; i < n4; i += stride) {
        const float4 f = in[i];
        ushort4 u;
        u.x = f2b(f.x); u.y = f2b(f.y); u.z = f2b(f.z); u.w = f2b(f.w);
        ((ushort4*)out)[i] = u;
    }
}

// all 4 weight matrices (w1in|w1out|w2in|w2out) in one launch
__global__ __launch_bounds__(256) void conv_w4(
    const float4* __restrict__ a, const float4* __restrict__ b,
    const float4* __restrict__ c, const float4* __restrict__ d,
    u16* __restrict__ oa, u16* __restrict__ ob,
    u16* __restrict__ oc, u16* __restrict__ od)
{
    const long long n1 = 442368, n2 = 589824, n3 = 1032192, n4 = 1179648;
    long long i = (long long)blockIdx.x * 256 + threadIdx.x;
    const long long stride = (long long)gridDim.x * 256;
    for (; i < n4; i += stride) {
        const float4* src; u16* dst; long long k;
        if (i < n1)      { src = a; dst = oa; k = i; }
        else if (i < n2) { src = b; dst = ob; k = i - n1; }
        else if (i < n3) { src = c; dst = oc; k = i - n2; }
        else             { src = d; dst = od; k = i - n3; }
        const float4 f = src[k];
        ushort4 u;
        u.x = f2b(f.x); u.y = f2b(f.y); u.z = f2b(f.z); u.w = f2b(f.w);
        ((ushort4*)dst)[k] = u;
    }
}

__global__ __launch_bounds__(256) void conv_patch(
    const float* __restrict__ img, u16* __restrict__ out)
{
    long long i = (long long)blockIdx.x * 256 + threadIdx.x;
    const long long n4 = 18432LL * 192;
    const long long stride = (long long)gridDim.x * 256;
    for (; i < n4; i += stride) {
        const long long r = i / 192; const int c4 = (int)(i % 192);
        const long long sr = (r / 576) * 577 + 1 + (r % 576);
        const float4 f = ((const float4*)img)[sr * 192 + c4];
        ushort4 u;
        u.x = f2b(f.x); u.y = f2b(f.y); u.z = f2b(f.z); u.w = f2b(f.w);
        ((ushort4*)out)[i] = u;
    }
}

__global__ __launch_bounds__(256) void cls_copy(
    const float* __restrict__ img, float* __restrict__ out)
{
    const int i = blockIdx.x * 256 + threadIdx.x;
    if (i < 32 * 768) {
        const int b = i / 768, c = i % 768;
        out[(long long)b * 577 * 768 + c] = img[(long long)b * 577 * 768 + c];
    }
}

// ---------------------------------------------------------------------------
static inline GemmGrp mkgrp(const u16* A, const u16* B, const float* bias,
    const float* resid, float* Cf, u16* Cb, int M, int N, int lda, int ldb,
    int ldc, float scale, int rgrp, long long rgA, long long rgoff, int ldr)
{
    GemmGrp g;
    g.A = A; g.B = B; g.bias = bias; g.resid = resid; g.Cf = Cf; g.Cb = Cb;
    g.M = M; g.N = N; g.lda = lda; g.ldb = ldb; g.ldc = ldc;
    g.scale = scale; g.rgrp = rgrp; g.rgA = rgA; g.rgoff = rgoff; g.ldr = ldr;
    return g;
}

static inline void launch_grp(hipStream_t s, const GemmGrp* gs, int ng, int K)
{
    G3 P;
    P.start[0] = 0;
    for (int i = 0; i < 3; ++i) {
        const GemmGrp& src = gs[i < ng ? i : ng - 1];
        P.g[i] = src;
        const int nb = (i < ng) ? (src.M / BM) * (src.N / BN) : 0;
        P.start[i + 1] = P.start[i] + nb;
    }
    P.K = K;
    gemm_grp<<<dim3((unsigned)P.start[3]), dim3(256), 0, s>>>(P);
}

extern "C" void kernel_launch(void* const* d_in, const int* in_sizes, int n_in,
                              void* d_out, int out_size, void* d_ws, size_t ws_size,
                              hipStream_t stream)
{
    (void)in_sizes; (void)n_in; (void)out_size; (void)ws_size;
    const float* img   = (const float*)d_in[0];
    const float* tac   = (const float*)d_in[1];
    const float* w1in  = (const float*)d_in[2];
    const float* b1in  = (const float*)d_in[3];
    const float* w1out = (const float*)d_in[4];
    const float* b1out = (const float*)d_in[5];
    const float* w2in  = (const float*)d_in[6];
    const float* b2in  = (const float*)d_in[7];
    const float* w2out = (const float*)d_in[8];
    const float* b2out = (const float*)d_in[9];
    const float* lng1  = (const float*)d_in[10];
    const float* lnb1  = (const float*)d_in[11];
    const float* lng2  = (const float*)d_in[12];
    const float* lnb2  = (const float*)d_in[13];
    float* out = (float*)d_out;

    const long long o_tac  = 32LL * 577 * 768;
    const long long o_attn = o_tac + 32LL * 256 * 768;
    const float qscale = 1.0f / sqrtf(96.0f);

    // ---- workspace arena ----
    u16* p = (u16*)d_ws;
    u16* tact_bf    = p; p += 8192LL * 768;
    u16* patch_bf   = p; p += 18432LL * 768;
    u16* w1in_bf    = p; p += 2304LL * 768;
    u16* w1out_bf   = p; p += 768LL * 768;
    u16* w2in_bf    = p; p += 2304LL * 768;
    u16* w2out_bf   = p; p += 768LL * 768;
    u16* tactnew_bf = p; p += 8192LL * 768;
    u16* Q1  = p; p += 8192LL * 768;
    u16* KV1 = p; p += 18432LL * 1536;
    u16* Vt1 = p; p += 256LL * 96 * 576;
    u16* AO1 = p; p += 8192LL * 768;
    u16* Q2  = p; p += 18432LL * 768;
    u16* KV2 = p; p += 8192LL * 1536;
    u16* Vt2 = p; p += 256LL * 96 * 256;
    u16* AO2 = p; p += 18432LL * 768;
    float* O1s = (float*)p; p += 2LL * 8192 * 768;
    float* O2s = (float*)p; p += 2LL * 18432 * 768;

    // ---- f32 -> bf16 conversions ----
    conv_f2b<<<1024, 256, 0, stream>>>((const float4*)tac, tact_bf, 8192LL * 192);
    conv_patch<<<1024, 256, 0, stream>>>(img, patch_bf);
    conv_w4<<<1024, 256, 0, stream>>>(
        (const float4*)w1in, (const float4*)w1out, (const float4*)w2in, (const float4*)w2out,
        w1in_bf, w1out_bf, w2in_bf, w2out_bf);
    cls_copy<<<96, 256, 0, stream>>>(img, out);

    // ---- merged projections: Q1 + KV1 + Q2 (independent; 2976 blocks) ----
    {
        GemmGrp gs[3] = {
            mkgrp(tact_bf,  w1in_bf,              b1in,       nullptr, nullptr, Q1,
                  8192, 768, 768, 768, 768, qscale, 1, 0, 0, 0),
            mkgrp(patch_bf, w1in_bf + 768LL*768,  b1in + 768, nullptr, nullptr, KV1,
                  18432, 1536, 768, 768, 1536, 1.0f, 1, 0, 0, 0),
            mkgrp(patch_bf, w2in_bf,              b2in,       nullptr, nullptr, Q2,
                  18432, 768, 768, 768, 768, qscale, 1, 0, 0, 0)
        };
        launch_grp(stream, gs, 3, 768);
    }

    // ================= phase 1: t2i MHA (q=tactile, kv=patch) =================
    transpose_v<<<dim3(9, 256), 256, 0, stream>>>(KV1 + 768, Vt1, 576, 1536);
    fused_attn<true><<<dim3(2, 256), 256, 0, stream>>>(
        Q1, KV1, Vt1, out + o_attn, AO1, 256, 576, 768, 1536, 768);
    {
        GemmGrp g = mkgrp(AO1, w1out_bf, b1out, tac, O1s, nullptr,
                          8192, 768, 768, 768, 768, 1.0f, 1, 768, 0, 0);
        launch_grp(stream, &g, 1, 768);
    }
    ln_k<<<8192 / 4, 256, 0, stream>>>(O1s, lng1, lnb1, out + o_tac, tactnew_bf,
        8192, 8192, 0, 0, 768);

    // ================= phase 2: i2t MHA (q=patch, kv=tactile_new) =============
    {
        GemmGrp g = mkgrp(tactnew_bf, w2in_bf + 768LL*768, b2in + 768, nullptr,
                          nullptr, KV2, 8192, 1536, 768, 768, 1536, 1.0f, 1, 0, 0, 0);
        launch_grp(stream, &g, 1, 768);
    }
    transpose_v<<<dim3(4, 256), 256, 0, stream>>>(KV2 + 768, Vt2, 256, 1536);
    fused_attn<false><<<dim3(5, 256), 256, 0, stream>>>(
        Q2, KV2, Vt2, nullptr, AO2, 576, 256, 768, 1536, 768);
    {
        GemmGrp g = mkgrp(AO2, w2out_bf, b2out, img, O2s, nullptr,
                          18432, 768, 768, 768, 768, 1.0f, 576, 577LL * 768, 768, 768);
        launch_grp(stream, &g, 1, 768);
    }
    ln_k<<<18432 / 4, 256, 0, stream>>>(O2s, lng2, lnb2, out, nullptr,
        18432, 576, 577LL * 768, 768, 768);
}